// Round 17
// baseline (3820.398 us; speedup 1.0000x reference)
//
#include <hip/hip_runtime.h>
#include <math.h>

// ---------------- problem constants ----------------
#define NV 65536              // conversation nodes
#define NT 65537              // + global vertex
#define DMOD 256              // hidden dim
#define DHID 1024             // HEADS * D
#define NEXPERT 8
#define CAPR (2*NV + NEXPERT*128)   // 132096 packed MoE rows (128-aligned buckets)
#define EMX 262208                  // >= actual edge count 262143

typedef __attribute__((ext_vector_type(4))) float f32x4;
typedef __attribute__((ext_vector_type(8))) short bf16x8;

// ---------------- ws layout (bytes) ----------------
static constexpr size_t kBig = (size_t)NT * DHID * sizeof(float);    // 268,439,552
static constexpr size_t oA   = 0;                // h buffer (h0 stride 256, later 1024)
static constexpr size_t oB   = kBig;             // xw / packed h1
static constexpr size_t nf4  = (size_t)NT * 16;  // NT x 4 floats
static constexpr size_t oSS  = 2*kBig;           // s_src
static constexpr size_t oSD  = oSS + nf4;        // s_dst
static constexpr size_t oZ   = oSD + nf4;        // z
static constexpr size_t oP   = oZ + nf4;         // p per edge (4 heads)
static constexpr size_t oTW  = oP  + (size_t)EMX*16;
static constexpr size_t oTI  = oTW + (size_t)NV*8;
static constexpr size_t oPL  = oTI + (size_t)NV*8;     // plist
static constexpr size_t oPE  = oPL + (size_t)CAPR*4;   // pexp
static constexpr size_t oPW  = oPE + (size_t)CAPR*4;   // ptw
static constexpr size_t oDG  = oPW + (size_t)CAPR*4;   // deg
static constexpr size_t oOF  = oDG + (size_t)(NT+3)*4; // csr offsets (NT+1)
static constexpr size_t oCC  = oOF + (size_t)(NT+3)*4; // csr fill counters
static constexpr size_t oCS  = oCC + (size_t)(NT+3)*4; // csr src
static constexpr size_t oCE  = oCS + (size_t)EMX*4;    // csr edge idx
static constexpr size_t oZS  = oCE + (size_t)EMX*4;    // 64 ints: [0..7]cnt [8..15]cnt2 [16]nbig [17]maskflag [18]nflag
static constexpr size_t o9   = oZS + 256;              // 9 ints padded offsets
static constexpr size_t oBG  = o9  + 64;               // big node list (64)
static constexpr size_t oBO  = oBG + 256;              // bigoff (66)
static constexpr size_t oMK  = oBO + 512;              // canonical int mask (NV)
static constexpr size_t oWC  = oMK + (size_t)NV*4;     // f64 gate weights, expert-major [8][2306]
static constexpr size_t oPBh = oWC + (size_t)8*2306*8;
static constexpr size_t zPB  = (size_t)256*2304*2;
static constexpr size_t oPBl = oPBh + zPB;
static constexpr size_t zG0  = (size_t)1024*256*2;
static constexpr size_t oG0h = oPBl + zPB;
static constexpr size_t oG0l = oG0h + zG0;
static constexpr size_t zG   = (size_t)1024*1024*2;
static constexpr size_t oG1h = oG0l + zG0;
static constexpr size_t oG1l = oG1h + zG;
static constexpr size_t oG2h = oG1l + zG;
static constexpr size_t oG2l = oG2h + zG;
static constexpr size_t zE   = (size_t)8*256*256*2;
static constexpr size_t oE1h = oG2l + zG;
static constexpr size_t oE1l = oE1h + zE;
static constexpr size_t oE2h = oE1l + zE;
static constexpr size_t oE2l = oE2h + zE;
static constexpr size_t oFL  = oE2l + zE;              // flagged node list (NV ints)
static constexpr size_t oGWT = oFL + (size_t)NV*4;     // gate_W^T f32 [8][256]
static constexpr size_t WSNEED = oGWT + (size_t)8*256*4;

// ---------------- bf16 split helpers ----------------
__device__ __forceinline__ unsigned f2bf(float f) {
  union { float f; unsigned u; } c; c.f = f;
  const unsigned u = c.u;
  return (u + 0x7FFFu + ((u >> 16) & 1u)) >> 16;
}
__device__ __forceinline__ float bf2f(unsigned h) {
  union { unsigned u; float f; } c; c.u = h << 16;
  return c.f;
}
__device__ __forceinline__ unsigned packsplit(float f) {
  const unsigned h = f2bf(f);
  const unsigned l = f2bf(f - bf2f(h));
  return (h << 16) | l;
}
__device__ __forceinline__ float unpk(unsigned u) {
  return bf2f(u >> 16) + bf2f(u & 0xFFFFu);
}
__device__ __forceinline__ void split8(const float4& v0, const float4& v1, uint4& uh, uint4& ul) {
  const float f[8] = {v0.x, v0.y, v0.z, v0.w, v1.x, v1.y, v1.z, v1.w};
  unsigned h[8], l[8];
  #pragma unroll
  for (int q = 0; q < 8; ++q) {
    h[q] = f2bf(f[q]);
    l[q] = f2bf(f[q] - bf2f(h[q]));
  }
  uh = make_uint4(h[0] | (h[1] << 16), h[2] | (h[3] << 16), h[4] | (h[5] << 16), h[6] | (h[7] << 16));
  ul = make_uint4(l[0] | (l[1] << 16), l[2] | (l[3] << 16), l[4] | (l[5] << 16), l[6] | (l[7] << 16));
}
// unpack 8 packed u32 (hi16|lo16) -> hi-pairs / lo-pairs (same layout as split8)
__device__ __forceinline__ void unpack8(const uint4& u0, const uint4& u1, uint4& uh, uint4& ul) {
  uh.x = (u0.x >> 16) | (u0.y & 0xFFFF0000u);  ul.x = (u0.x & 0xFFFFu) | (u0.y << 16);
  uh.y = (u0.z >> 16) | (u0.w & 0xFFFF0000u);  ul.y = (u0.z & 0xFFFFu) | (u0.w << 16);
  uh.z = (u1.x >> 16) | (u1.y & 0xFFFF0000u);  ul.z = (u1.x & 0xFFFFu) | (u1.y << 16);
  uh.w = (u1.z >> 16) | (u1.w & 0xFFFF0000u);  ul.w = (u1.z & 0xFFFFu) | (u1.w << 16);
}

// ---------------- in-place f32 -> packed split-bf16 ----------------
__global__ __launch_bounds__(256) void k_pack(float* __restrict__ buf, size_t n) {
  const size_t i = ((size_t)blockIdx.x * 256 + threadIdx.x) * 4;
  if (i >= n) return;
  float4 v = *(float4*)(buf + i);
  uint4 r;
  r.x = packsplit(v.x); r.y = packsplit(v.y); r.z = packsplit(v.z); r.w = packsplit(v.w);
  *(uint4*)(buf + i) = r;
}
// pack just the big-node rows (after agg_big's f32 atomics)
__global__ __launch_bounds__(256) void k_pack_rows(float* __restrict__ hA,
                                                  const int* __restrict__ nbig,
                                                  const int* __restrict__ big) {
  const int nb = *nbig;
  for (int bi = blockIdx.x; bi < nb; bi += gridDim.x) {
    const int node = big[bi];
    float* row = hA + (size_t)node * DHID;
    for (int c = threadIdx.x; c < DHID; c += 256)
      ((unsigned*)row)[c] = packsplit(row[c]);
  }
}

// ---------------- weight transpose + bf16-split -> FRAGMENT-MAJOR global layout ----------
// out layout (shorts): off = ((n>>4)*(Kout/8) + (k>>3))*128 + (n&15)*8 + (k&7)
__global__ __launch_bounds__(256) void k_tsplit(
    const float* __restrict__ in, int Kin, int Nin, int Kout, int koff,
    long ibstride, long obstride,
    unsigned short* __restrict__ oh, unsigned short* __restrict__ ol)
{
  __shared__ float t[64][68];
  const int b = blockIdx.z;
  in += (size_t)b * ibstride;
  oh += (size_t)b * obstride;
  ol += (size_t)b * obstride;
  const int k0 = blockIdx.x << 6, n0 = blockIdx.y << 6;
  const int tid = threadIdx.x;
  #pragma unroll
  for (int p = 0; p < 4; ++p) {
    const int r = (tid >> 4) + (p << 4);
    const int c4 = (tid & 15) << 2;
    *(float4*)&t[r][c4] = *(const float4*)(in + (size_t)(k0 + r) * Nin + n0 + c4);
  }
  __syncthreads();
  #pragma unroll
  for (int p = 0; p < 4; ++p) {
    const int n = n0 + (tid >> 4) + (p << 4);
    const int k4 = (tid & 15) << 2;
    unsigned h[4], l[4];
    #pragma unroll
    for (int q = 0; q < 4; ++q) {
      const float f = t[k4 + q][n - n0];
      h[q] = f2bf(f);
      l[q] = f2bf(f - bf2f(h[q]));
    }
    const int kg = koff + k0 + k4;
    const size_t off = ((size_t)(n >> 4) * (Kout >> 3) + (kg >> 3)) * 128 + (n & 15) * 8 + (kg & 7);
    *(uint2*)(oh + off) = make_uint2(h[0] | (h[1] << 16), h[2] | (h[3] << 16));
    *(uint2*)(ol + off) = make_uint2(l[0] | (l[1] << 16), l[2] | (l[3] << 16));
  }
}

// ---------------- GAT GEMM: 32-row x 128-col waves (halved A LDS reads) ----------------
// Each wave owns rows [32w,32w+32) x ALL 128 cols: 2 A row-frags (distinct per wave,
// 4 ds_reads) + 8 B col-frags direct from global (two register batches of 4).
// Accumulation order per output element identical to gemm_m -> bit-identical.
__global__ __launch_bounds__(256) void gemm_w(
    int M, int K,
    const unsigned* __restrict__ A0,
    const unsigned short* __restrict__ BTh, const unsigned short* __restrict__ BTl,
    float* __restrict__ C, int ldc)
{
  __shared__ uint4 AshF[2][512];
  __shared__ uint4 AslF[2][512];
  const int tid = threadIdx.x;
  const int b = blockIdx.x;
  const int t = (b & 7) * 513 + (b >> 3);
  const int bn0 = (t & 7) << 7;
  const int bm0 = (t >> 3) << 7;
  const int wid = tid >> 6, lane = tid & 63;
  const int l15 = lane & 15, lg = lane >> 4;
  f32x4 acc[2][8];
  #pragma unroll
  for (int i = 0; i < 2; ++i)
    #pragma unroll
    for (int j = 0; j < 8; ++j) acc[i][j] = (f32x4)0.f;

  const int srow = tid >> 2;
  const int lgw  = tid & 3;
  const int k8 = lgw << 3;
  const size_t nfrow = (size_t)K * 2;    // uint4 per n-fragment row
  const uint4* bph = (const uint4*)BTh + (size_t)(bn0 >> 4) * nfrow + lane;
  const uint4* bpl = (const uint4*)BTl + (size_t)(bn0 >> 4) * nfrow + lane;
  const int ridx = lane ^ lg;
  const int nkt = K >> 5;
  uint4 su0[2], su1[2];

  auto loadA = [&](int kt) {
    const int kk = (kt << 5) + k8;
    #pragma unroll
    for (int p = 0; p < 2; ++p) {
      const int grow = bm0 + srow + (p << 6);
      su0[p] = make_uint4(0, 0, 0, 0); su1[p] = su0[p];
      if (grow < M) {
        const unsigned* ap = A0 + (size_t)grow * K + kk;
        su0[p] = *(const uint4*)ap; su1[p] = *(const uint4*)(ap + 4);
      }
    }
  };
  auto storeA = [&](int buf) {
    #pragma unroll
    for (int p = 0; p < 2; ++p) {
      uint4 uh, ul;
      unpack8(su0[p], su1[p], uh, ul);
      const int r = srow + (p << 6);
      const int wi = ((r >> 4) << 6) + (lgw << 4) + ((r & 15) ^ lgw);
      AshF[buf][wi] = uh;
      AslF[buf][wi] = ul;
    }
  };

  loadA(0);
  storeA(0);
  __syncthreads();
  for (int kt = 0; kt < nkt; ++kt) {
    const int cur = kt & 1;
    // A fragments: wave w owns row-frags {2w, 2w+1} (no duplication across waves)
    bf16x8 ah[2], al[2];
    #pragma unroll
    for (int i = 0; i < 2; ++i) {
      ah[i] = ((const bf16x8*)AshF[cur])[(((wid << 1) + i) << 6) + ridx];
      al[i] = ((const bf16x8*)AslF[cur])[(((wid << 1) + i) << 6) + ridx];
    }
    if (kt + 1 < nkt) loadA(kt + 1);
    // B batch 0 (col-frags 0..3) + MFMA
    bf16x8 bh[4], bl[4];
    #pragma unroll
    for (int j = 0; j < 4; ++j) {
      bh[j] = *(const bf16x8*)(bph + (size_t)j * nfrow + (kt << 6));
      bl[j] = *(const bf16x8*)(bpl + (size_t)j * nfrow + (kt << 6));
    }
    #pragma unroll
    for (int i = 0; i < 2; ++i)
      #pragma unroll
      for (int j = 0; j < 4; ++j) {
        f32x4 t2 = acc[i][j];
        t2 = __builtin_amdgcn_mfma_f32_16x16x32_bf16(al[i], bh[j], t2, 0, 0, 0);
        t2 = __builtin_amdgcn_mfma_f32_16x16x32_bf16(ah[i], bl[j], t2, 0, 0, 0);
        t2 = __builtin_amdgcn_mfma_f32_16x16x32_bf16(ah[i], bh[j], t2, 0, 0, 0);
        acc[i][j] = t2;
      }
    // B batch 1 (col-frags 4..7) + MFMA
    #pragma unroll
    for (int j = 0; j < 4; ++j) {
      bh[j] = *(const bf16x8*)(bph + (size_t)(j + 4) * nfrow + (kt << 6));
      bl[j] = *(const bf16x8*)(bpl + (size_t)(j + 4) * nfrow + (kt << 6));
    }
    #pragma unroll
    for (int i = 0; i < 2; ++i)
      #pragma unroll
      for (int j = 0; j < 4; ++j) {
        f32x4 t2 = acc[i][j + 4];
        t2 = __builtin_amdgcn_mfma_f32_16x16x32_bf16(al[i], bh[j], t2, 0, 0, 0);
        t2 = __builtin_amdgcn_mfma_f32_16x16x32_bf16(ah[i], bl[j], t2, 0, 0, 0);
        t2 = __builtin_amdgcn_mfma_f32_16x16x32_bf16(ah[i], bh[j], t2, 0, 0, 0);
        acc[i][j + 4] = t2;
      }
    if (kt + 1 < nkt) storeA(cur ^ 1);
    __syncthreads();
  }
  // epilogue: rows bm0 + 32*wid + i*16 + lg*4 + v, cols bn0 + j*16 + l15
  const int r0 = bm0 + (wid << 5);
  #pragma unroll
  for (int i = 0; i < 2; ++i) {
    #pragma unroll
    for (int v = 0; v < 4; ++v) {
      const int r = r0 + (i << 4) + (lg << 2) + v;
      if (r >= M) continue;
      #pragma unroll
      for (int j = 0; j < 8; ++j) {
        const int c = bn0 + (j << 4) + l15;
        C[(size_t)r * ldc + c] = acc[i][j][v];
      }
    }
  }
}

// ---------------- split-bf16 MFMA GEMM (proj / MoE modes; validated path) ----------------
// MODE 1: proj (3 K-segment f32 A + split8); epilogue writes PACKED x
// MODE 2: MoE W1 (gather PACKED A rows via plist; per-expert B/bias)
// MODE 3: MoE W2 (packed A=hB; per-expert B/bias; ptw-scaled f32 atomic scatter-add)
template<int MODE>
__global__ __launch_bounds__(256) void gemm_m(
    int M, int K,
    const float* __restrict__ A0, int lda0,
    const float* __restrict__ A1, int lda1,
    const float* __restrict__ A2, int lda2,
    const unsigned short* __restrict__ BTh, const unsigned short* __restrict__ BTl,
    long bstride,
    float* __restrict__ C, int ldc,
    const float* __restrict__ bias0,
    const int* __restrict__ mask, const float* __restrict__ mtok,
    const float* __restrict__ biasx1, const float* __restrict__ biasx2,
    const int* __restrict__ plist, const int* __restrict__ pexp, const float* __restrict__ ptw,
    const float* __restrict__ gsrc)
{
  __shared__ uint4 AshF[2][512];
  __shared__ uint4 AslF[2][512];
  const int tid = threadIdx.x;
  const int bn0 = blockIdx.x << 7;
  const int bm0 = blockIdx.y << 7;
  int eb = 0;
  if (MODE == 2 || MODE == 3) eb = pexp[bm0];
  const int wid = tid >> 6, lane = tid & 63;
  const int wm = wid >> 1, wn = wid & 1;
  const int l15 = lane & 15, lg = lane >> 4;
  f32x4 acc[4][4];
  #pragma unroll
  for (int i = 0; i < 4; ++i)
    #pragma unroll
    for (int j = 0; j < 4; ++j) acc[i][j] = (f32x4)0.f;

  const int srow = tid >> 2;
  const int lgw  = tid & 3;
  const int k8 = lgw << 3;
  const size_t nfrow = (size_t)K * 2;
  const uint4* bph = (const uint4*)(BTh + (size_t)eb * bstride)
                     + (size_t)((bn0 >> 4) + (wn << 2)) * nfrow + lane;
  const uint4* bpl = (const uint4*)(BTl + (size_t)eb * bstride)
                     + (size_t)((bn0 >> 4) + (wn << 2)) * nfrow + lane;
  const int ridx = lane ^ lg;
  int nodes[2] = {0, 0};
  if (MODE == 2) {
    nodes[0] = plist[bm0 + srow];
    nodes[1] = plist[bm0 + srow + 64];
  }
  const int nkt = K >> 5;
  uint4 su0[2], su1[2];
  float4 sv0[2], sv1[2];

  auto loadA = [&](int kt) {
    const int kk = (kt << 5) + k8;
    #pragma unroll
    for (int p = 0; p < 2; ++p) {
      const int grow = bm0 + srow + (p << 6);
      if (MODE == 1) {
        const float* ap; int kloc;
        if (kk < 1024)      { ap = A0 + (size_t)grow * lda0; kloc = kk; }
        else if (kk < 1536) { ap = A1 + (size_t)grow * lda1; kloc = kk - 1024; }
        else                { ap = A2 + (size_t)grow * lda2; kloc = kk - 1536; }
        sv0[p] = *(const float4*)(ap + kloc);
        sv1[p] = *(const float4*)(ap + kloc + 4);
      } else if (MODE == 2) {
        const int nd = nodes[p];
        su0[p] = make_uint4(0, 0, 0, 0); su1[p] = su0[p];
        if (nd >= 0) {
          const unsigned* ap = (const unsigned*)gsrc + (size_t)nd * DMOD + kk;
          su0[p] = *(const uint4*)ap; su1[p] = *(const uint4*)(ap + 4);
        }
      } else {
        const unsigned* ap = (const unsigned*)A0 + (size_t)grow * lda0 + kk;
        su0[p] = *(const uint4*)ap; su1[p] = *(const uint4*)(ap + 4);
      }
    }
  };
  auto storeA = [&](int buf) {
    #pragma unroll
    for (int p = 0; p < 2; ++p) {
      uint4 uh, ul;
      if (MODE == 1) split8(sv0[p], sv1[p], uh, ul);
      else           unpack8(su0[p], su1[p], uh, ul);
      const int r = srow + (p << 6);
      const int wi = ((r >> 4) << 6) + (lgw << 4) + ((r & 15) ^ lgw);
      AshF[buf][wi] = uh;
      AslF[buf][wi] = ul;
    }
  };

  loadA(0);
  storeA(0);
  __syncthreads();
  for (int kt = 0; kt < nkt; ++kt) {
    const int cur = kt & 1;
    bf16x8 bh[4], bl[4];
    #pragma unroll
    for (int j = 0; j < 4; ++j) {
      bh[j] = *(const bf16x8*)(bph + (size_t)j * nfrow + (kt << 6));
      bl[j] = *(const bf16x8*)(bpl + (size_t)j * nfrow + (kt << 6));
    }
    bf16x8 ah[4], al[4];
    #pragma unroll
    for (int i = 0; i < 4; ++i) {
      ah[i] = ((const bf16x8*)AshF[cur])[(((wm << 2) + i) << 6) + ridx];
      al[i] = ((const bf16x8*)AslF[cur])[(((wm << 2) + i) << 6) + ridx];
    }
    if (kt + 1 < nkt) loadA(kt + 1);
    #pragma unroll
    for (int i = 0; i < 4; ++i)
      #pragma unroll
      for (int j = 0; j < 4; ++j) {
        f32x4 t = acc[i][j];
        t = __builtin_amdgcn_mfma_f32_16x16x32_bf16(al[i], bh[j], t, 0, 0, 0);
        t = __builtin_amdgcn_mfma_f32_16x16x32_bf16(ah[i], bl[j], t, 0, 0, 0);
        t = __builtin_amdgcn_mfma_f32_16x16x32_bf16(ah[i], bh[j], t, 0, 0, 0);
        acc[i][j] = t;
      }
    if (kt + 1 < nkt) storeA(cur ^ 1);
    __syncthreads();
  }
  // ---- epilogue (C/D map: col = lane&15, row = (lane>>4)*4 + reg) ----
  const int r0 = bm0 + (wm << 6), c0 = bn0 + (wn << 6);
  #pragma unroll
  for (int i = 0; i < 4; ++i) {
    #pragma unroll
    for (int v = 0; v < 4; ++v) {
      const int r = r0 + (i << 4) + (lg << 2) + v;
      int node = 0; float pw = 0.f; int msk = 0;
      if (MODE == 3) { node = plist[r]; if (node < 0) continue; pw = ptw[r]; }
      if (MODE == 1) msk = mask[r];
      #pragma unroll
      for (int j = 0; j < 4; ++j) {
        const int c = c0 + (j << 4) + l15;
        const float a = acc[i][j][v];
        if (MODE == 1) {
          float val = (a + bias0[c] + biasx1[c] + biasx2[c]) * (1.f / 3.f);
          if (msk) val = mtok[c];
          ((unsigned*)C)[(size_t)r * ldc + c] = packsplit(val);
        } else if (MODE == 2) {
          C[(size_t)r * ldc + c] = a + bias0[eb * DMOD + c];
        } else {
          atomicAdd(C + (size_t)node * DMOD + c, (a + bias0[eb * DMOD + c]) * pw);
        }
      }
    }
  }
}

// ---------------- mask dtype detect + canonicalize ----------------
__global__ void k_mask_flag(const unsigned int* __restrict__ mw, int* __restrict__ flag) {
  const int i = blockIdx.x * 256 + threadIdx.x;
  if (i < 16384 && (mw[i] & 0xFFFFFF00u)) atomicOr(flag, 1);
}
__global__ void k_mask_canon(const void* __restrict__ m, const int* __restrict__ flag, int* __restrict__ out) {
  const int i = blockIdx.x * 256 + threadIdx.x;
  if (i >= NV) return;
  out[i] = (*flag) ? (int)((const unsigned char*)m)[i] : ((const int*)m)[i];
}

// ---------------- f64-true gate weights, EXPERT-MAJOR: Wc[e][2306] ----------------
__global__ __launch_bounds__(64) void k_wc(
    const float* __restrict__ Wv, const float* __restrict__ Wa, const float* __restrict__ Wt,
    const float* __restrict__ bv, const float* __restrict__ ba, const float* __restrict__ bt,
    const float* __restrict__ mtok, const float* __restrict__ gW, const float* __restrict__ gb,
    double* __restrict__ Wc)
{
  const int r = blockIdx.x;
  const int l = threadIdx.x;
  float4 w;
  if (r < 1024)       w = *(const float4*)(Wv + (size_t)r * DMOD + l * 4);
  else if (r < 1536)  w = *(const float4*)(Wa + (size_t)(r - 1024) * DMOD + l * 4);
  else if (r < 2304)  w = *(const float4*)(Wt + (size_t)(r - 1536) * DMOD + l * 4);
  else if (r == 2304) {
    const float4 b0 = *(const float4*)(bv + l * 4);
    const float4 b1 = *(const float4*)(ba + l * 4);
    const float4 b2 = *(const float4*)(bt + l * 4);
    w = make_float4(b0.x + b1.x + b2.x, b0.y + b1.y + b2.y, b0.z + b1.z + b2.z, b0.w + b1.w + b2.w);
  } else              w = *(const float4*)(mtok + l * 4);
  const float wq[4] = {w.x, w.y, w.z, w.w};
  double acc[NEXPERT];
  #pragma unroll
  for (int e = 0; e < NEXPERT; ++e) acc[e] = 0.0;
  #pragma unroll
  for (int q = 0; q < 4; ++q) {
    const int d = l * 4 + q;
    #pragma unroll
    for (int e = 0; e < NEXPERT; ++e)
      acc[e] += (double)wq[q] * (double)gW[d * NEXPERT + e];
  }
  #pragma unroll
  for (int e = 0; e < NEXPERT; ++e) {
    #pragma unroll
    for (int o = 32; o > 0; o >>= 1) acc[e] += __shfl_xor(acc[e], o);
  }
  if (l == 0) {
    const double s = (r <= 2304) ? (1.0 / 3.0) : 1.0;
    #pragma unroll
    for (int e = 0; e < NEXPERT; ++e) {
      double v = acc[e] * s;
      if (r >= 2304) v += (double)gb[e];
      Wc[(size_t)e * 2306 + r] = v;
    }
  }
}

// ---------------- gate_W^T f32 [8][256] ----------------
__global__ void k_gwt(const float* __restrict__ gW, float* __restrict__ gWt) {
  const int i = blockIdx.x * 256 + threadIdx.x;   // i = e*256 + d
  if (i >= 8 * 256) return;
  const int e = i >> 8, d = i & 255;
  gWt[i] = gW[d * NEXPERT + e];
}

// ---------------- fast f32 gate from packed x; flag near-ties (2nd vs 3rd gap) ------------
__global__ __launch_bounds__(256) void k_gate_f32(
    const unsigned* __restrict__ xp, const float* __restrict__ gWt, const float* __restrict__ gb,
    const double* __restrict__ Wc, const int* __restrict__ mask,
    float* __restrict__ tw, int* __restrict__ ti,
    int* __restrict__ flags, int* __restrict__ nflag)
{
  const int wv = (blockIdx.x * 256 + threadIdx.x) >> 6;
  const int lane = threadIdx.x & 63;
  if (wv >= NV) return;
  const int msk = mask[wv];
  float acc[NEXPERT];
  #pragma unroll
  for (int e = 0; e < NEXPERT; ++e) acc[e] = 0.f;
  if (!msk) {
    const uint4 u = *(const uint4*)(xp + (size_t)wv * DMOD + lane * 4);
    const float xv[4] = {unpk(u.x), unpk(u.y), unpk(u.z), unpk(u.w)};
    #pragma unroll
    for (int e = 0; e < NEXPERT; ++e) {
      const float4 w = *(const float4*)(gWt + e * DMOD + lane * 4);
      acc[e] = xv[0] * w.x + xv[1] * w.y + xv[2] * w.z + xv[3] * w.w;
    }
    #pragma unroll
    for (int e = 0; e < NEXPERT; ++e) {
      #pragma unroll
      for (int o = 32; o > 0; o >>= 1) acc[e] += __shfl_xor(acc[e], o);
    }
  }
  if (lane == 0) {
    float le[NEXPERT];
    #pragma unroll
    for (int e = 0; e < NEXPERT; ++e)
      le[e] = msk ? (float)Wc[(size_t)e * 2306 + 2305] : (acc[e] + gb[e]);
    int b0 = -1, b1 = -1;
    float v0 = -1e30f, v1 = -1e30f, v2 = -1e30f;
    #pragma unroll
    for (int e = 0; e < NEXPERT; ++e) {
      const float v = le[e];
      if (v > v0)      { v2 = v1; v1 = v0; b1 = b0; v0 = v; b0 = e; }
      else if (v > v1) { v2 = v1; v1 = v; b1 = e; }
      else if (v > v2) { v2 = v; }
    }
    const double w0 = 1.0 / (1.0 + exp((double)v1 - (double)v0));
    tw[wv * 2 + 0] = (float)w0;
    tw[wv * 2 + 1] = (float)(1.0 - w0);
    ti[wv * 2 + 0] = b0;
    ti[wv * 2 + 1] = b1;
    if (v1 - v2 < 1e-3f) {
      const int idx = atomicAdd(nflag, 1);
      if (idx < NV) flags[idx] = wv;
    }
  }
}

// ---------------- f64 exact gate for flagged nodes ----------------
__global__ __launch_bounds__(256) void k_gate_fix(
    const float* __restrict__ fv, const float* __restrict__ fa, const float* __restrict__ ft,
    const double* __restrict__ Wc, const int* __restrict__ mask,
    const int* __restrict__ flags, const int* __restrict__ nflag,
    float* __restrict__ tw, int* __restrict__ ti)
{
  int nf = *nflag; if (nf > NV) nf = NV;
  const int lane = threadIdx.x & 63;
  const int wix = (blockIdx.x * 256 + threadIdx.x) >> 6;
  const int nw = gridDim.x * 4;
  for (int idx = wix; idx < nf; idx += nw) {
    const int node = flags[idx];
    const int msk = mask[node];
    double acc[NEXPERT];
    #pragma unroll
    for (int e = 0; e < NEXPERT; ++e) acc[e] = 0.0;
    if (!msk) {
      #pragma unroll
      for (int c = 0; c < 9; ++c) {
        const int kg0 = c * 256 + lane * 4;
        const float* base; int kloc;
        if (kg0 < 1024)      { base = fv + (size_t)node * 1024; kloc = kg0; }
        else if (kg0 < 1536) { base = fa + (size_t)node * 512;  kloc = kg0 - 1024; }
        else                 { base = ft + (size_t)node * 768;  kloc = kg0 - 1536; }
        const float4 f = *(const float4*)(base + kloc);
        const float fq[4] = {f.x, f.y, f.z, f.w};
        #pragma unroll
        for (int q = 0; q < 4; ++q) {
          #pragma unroll
          for (int e = 0; e < NEXPERT; ++e)
            acc[e] += (double)fq[q] * Wc[(size_t)e * 2306 + kg0 + q];
        }
      }
      #pragma unroll
      for (int e = 0; e < NEXPERT; ++e) {
        #pragma unroll
        for (int o = 32; o > 0; o >>= 1) acc[e] += __shfl_xor(acc[e], o);
      }
    }
    if (lane == 0) {
      double le[NEXPERT];
      #pragma unroll
      for (int e = 0; e < NEXPERT; ++e)
        le[e] = msk ? Wc[(size_t)e * 2306 + 2305] : (acc[e] + Wc[(size_t)e * 2306 + 2304]);
      int b0 = -1, b1 = -1;
      double v0 = -1e300, v1 = -1e300;
      for (int e = 0; e < NEXPERT; ++e) {
        if (le[e] > v0) { v1 = v0; b1 = b0; v0 = le[e]; b0 = e; }
        else if (le[e] > v1) { v1 = le[e]; b1 = e; }
      }
      const double w0 = 1.0 / (1.0 + exp(v1 - v0));
      tw[node * 2 + 0] = (float)w0;
      tw[node * 2 + 1] = (float)(1.0 - w0);
      ti[node * 2 + 0] = b0;
      ti[node * 2 + 1] = b1;
    }
  }
}

// ---------------- expert counts from final ti (block-aggregated) ----------------
__global__ __launch_bounds__(256) void k_count(const int* __restrict__ ti, int* __restrict__ counts) {
  __shared__ int lcnt[NEXPERT];
  const int tid = threadIdx.x;
  const int n = blockIdx.x * 256 + tid;
  if (tid < NEXPERT) lcnt[tid] = 0;
  __syncthreads();
  const int e0 = ti[n * 2 + 0];
  const int e1 = ti[n * 2 + 1];
  if ((unsigned)e0 < NEXPERT) atomicAdd(&lcnt[e0], 1);
  if ((unsigned)e1 < NEXPERT) atomicAdd(&lcnt[e1], 1);
  __syncthreads();
  if (tid < NEXPERT && lcnt[tid] > 0) atomicAdd(&counts[tid], lcnt[tid]);
}

__global__ void k_moe_offs(const int* __restrict__ counts, int* __restrict__ offs9) {
  if (threadIdx.x == 0 && blockIdx.x == 0) {
    int o = 0;
    for (int e = 0; e < NEXPERT; ++e) { offs9[e] = o; o += (counts[e] + 127) & ~127; }
    offs9[NEXPERT] = o;
  }
}
__global__ void k_moe_fill(const int* __restrict__ offs9, int* __restrict__ plist, int* __restrict__ pexp) {
  const int r = blockIdx.x * 256 + threadIdx.x;
  if (r >= CAPR) return;
  int e = 0;
  while (e < NEXPERT - 1 && r >= offs9[e + 1]) ++e;
  pexp[r] = e;
  plist[r] = -1;
}
__global__ __launch_bounds__(256) void k_moe_scatter(
    const int* __restrict__ ti, const float* __restrict__ tw,
    const int* __restrict__ offs9, int* __restrict__ cnt2,
    int* __restrict__ plist, float* __restrict__ ptw) {
  __shared__ int lcnt[NEXPERT];
  __shared__ int lbase[NEXPERT];
  const int tid = threadIdx.x;
  const int n = blockIdx.x * 256 + tid;
  if (tid < NEXPERT) lcnt[tid] = 0;
  __syncthreads();
  const int e0 = ti[n * 2 + 0];
  const int e1 = ti[n * 2 + 1];
  const bool v0 = (unsigned)e0 < NEXPERT;
  const bool v1 = (unsigned)e1 < NEXPERT;
  int r0 = 0, r1 = 0;
  if (v0) r0 = atomicAdd(&lcnt[e0], 1);
  if (v1) r1 = atomicAdd(&lcnt[e1], 1);
  __syncthreads();
  if (tid < NEXPERT && lcnt[tid] > 0) lbase[tid] = atomicAdd(&cnt2[tid], lcnt[tid]);
  __syncthreads();
  if (v0) {
    const int pos = offs9[e0] + lbase[e0] + r0;
    if ((unsigned)pos < CAPR) { plist[pos] = n; ptw[pos] = tw[n * 2 + 0]; }
  }
  if (v1) {
    const int pos = offs9[e1] + lbase[e1] + r1;
    if ((unsigned)pos < CAPR) { plist[pos] = n; ptw[pos] = tw[n * 2 + 1]; }
  }
}

// ---------------- LN + exact GELU on packed rows (writes PACKED split-bf16) ----------------
__global__ __launch_bounds__(256) void k_ln_gelu(
    float* __restrict__ h1, const int* __restrict__ plist, const int* __restrict__ pexp,
    const float* __restrict__ g, const float* __restrict__ beta)
{
  const int r = blockIdx.x;
  if (plist[r] < 0) return;
  const int e = pexp[r];
  const int t = threadIdx.x;
  __shared__ float red[4];
  __shared__ float bc;
  const float v = h1[(size_t)r * DMOD + t];
  float s = v;
  #pragma unroll
  for (int o = 32; o > 0; o >>= 1) s += __shfl_xor(s, o);
  if ((t & 63) == 0) red[t >> 6] = s;
  __syncthreads();
  if (t == 0) bc = (red[0] + red[1] + red[2] + red[3]) * (1.f / 256.f);
  __syncthreads();
  const float mu = bc;
  const float dv = v - mu;
  float s2 = dv * dv;
  #pragma unroll
  for (int o = 32; o > 0; o >>= 1) s2 += __shfl_xor(s2, o);
  __syncthreads();
  if ((t & 63) == 0) red[t >> 6] = s2;
  __syncthreads();
  if (t == 0) bc = (red[0] + red[1] + red[2] + red[3]) * (1.f / 256.f);
  __syncthreads();
  const float var = bc;
  const float y = dv * rsqrtf(var + 1e-5f) * g[e * DMOD + t] + beta[e * DMOD + t];
  const float gl = y * 0.5f * (1.f + erff(y * 0.70710678118654752f));
  ((unsigned*)h1)[(size_t)r * DMOD + t] = packsplit(gl);
}

__global__ void k_set_global(float* __restrict__ h0, const float* __restrict__ gv) {
  h0[(size_t)NV * DMOD + threadIdx.x] = gv[threadIdx.x];
}

// ---------------- GAT attention pieces ----------------
__global__ __launch_bounds__(256) void k_attn_s(
    const float* __restrict__ xw, const float* __restrict__ aS, const float* __restrict__ aD,
    float* __restrict__ sS, float* __restrict__ sD)
{
  const int wv = (blockIdx.x * 256 + threadIdx.x) >> 6;
  const int lane = threadIdx.x & 63;
  if (wv >= NT) return;
  const int h = lane >> 4, j = lane & 15;
  const float* row = xw + (size_t)wv * DHID + h * DMOD + j * 16;
  const float* av = aS + h * DMOD + j * 16;
  const float* dv = aD + h * DMOD + j * 16;
  float ps = 0.f, pd = 0.f;
  #pragma unroll
  for (int q = 0; q < 16; q += 4) {
    const float4 xv = *(const float4*)(row + q);
    const float4 a4 = *(const float4*)(av + q);
    const float4 d4 = *(const float4*)(dv + q);
    ps += xv.x * a4.x + xv.y * a4.y + xv.z * a4.z + xv.w * a4.w;
    pd += xv.x * d4.x + xv.y * d4.y + xv.z * d4.z + xv.w * d4.w;
  }
  #pragma unroll
  for (int o = 1; o <= 8; o <<= 1) { ps += __shfl_xor(ps, o); pd += __shfl_xor(pd, o); }
  if (j == 0) { sS[(size_t)wv * 4 + h] = ps; sD[(size_t)wv * 4 + h] = pd; }
}

__global__ __launch_bounds__(256) void k_edge_z(
    const int* __restrict__ esrc, const int* __restrict__ edst,
    const float* __restrict__ sS, const float* __restrict__ sD,
    float* __restrict__ p, float* __restrict__ z, int E)
{
  const int i = blockIdx.x * 256 + threadIdx.x;
  const bool valid = i < E;
  const int ic = valid ? i : (E - 1);
  const int dst = edst[ic];
  const int src = esrc[ic];
  const float4 a = *(const float4*)(sS + (size_t)src * 4);
  const float4 b = *(const float4*)(sD + (size_t)dst * 4);
  float e4[4] = {a.x + b.x, a.y + b.y, a.z + b.z, a.w + b.w};
  float pv[4];
  #pragma unroll
  for (int h = 0; h < 4; ++h) {
    const float e = e4[h] > 0.f ? e4[h] : 0.2f * e4[h];
    pv[h] = expf(e);
  }
  if (valid) *(float4*)(p + (size_t)i * 4) = make_float4(pv[0], pv[1], pv[2], pv[3]);
  float c4[4];
  #pragma unroll
  for (int h = 0; h < 4; ++h) c4[h] = valid ? pv[h] : 0.f;
  const int d0 = __shfl(dst, 0);
  if (__all(dst == d0)) {
    #pragma unroll
    for (int h = 0; h < 4; ++h) {
      #pragma unroll
      for (int o = 1; o <= 32; o <<= 1) c4[h] += __shfl_xor(c4[h], o);
    }
    if ((threadIdx.x & 63) == 0) {
      #pragma unroll
      for (int h = 0; h < 4; ++h) atomicAdd(&z[(size_t)d0 * 4 + h], c4[h]);
    }
  } else if (valid) {
    #pragma unroll
    for (int h = 0; h < 4; ++h) atomicAdd(&z[(size_t)dst * 4 + h], c4[h]);
  }
}

// ---------------- CSR build (wave-aggregated atomics for hot destinations) ----------------
__global__ void k_deg(const int* __restrict__ edst, int* __restrict__ deg, int E) {
  const int i = blockIdx.x * 256 + threadIdx.x;
  const bool valid = i < E;
  const int ic = valid ? i : (E - 1);
  const int d = edst[ic];
  const int d0 = __shfl(d, 0);
  if (__all(d == d0)) {
    const unsigned long long m = __ballot(valid);
    if ((threadIdx.x & 63) == 0) atomicAdd(&deg[d0], __popcll(m));
  } else if (valid) {
    atomicAdd(&deg[d], 1);
  }
}
__global__ __launch_bounds__(1024) void k_scan(const int* __restrict__ deg, int* __restrict__ offs) {
  __shared__ int part[1024];
  const int t = threadIdx.x;
  const int s0 = t * 65;
  int sum = 0;
  for (int j = 0; j < 65; ++j) { const int idx = s0 + j; if (idx < NT) sum += deg[idx]; }
  part[t] = sum;
  __syncthreads();
  for (int off = 1; off < 1024; off <<= 1) {
    const int v = (t >= off) ? part[t - off] : 0;
    __syncthreads();
    part[t] += v;
    __syncthreads();
  }
  int run = part[t] - sum;
  for (int j = 0; j < 65; ++j) {
    const int idx = s0 + j;
    if (idx < NT) { offs[idx] = run; run += deg[idx]; }
  }
  if (t == 1023) offs[NT] = part[1023];
}
__global__ void k_csr_scatter(const int* __restrict__ esrc, const int* __restrict__ edst,
                              const int* __restrict__ offs, int* __restrict__ ccnt,
                              int* __restrict__ csrc, int* __restrict__ ceid, int E) {
  const int i = blockIdx.x * 256 + threadIdx.x;
  const bool valid = i < E;
  const int ic = valid ? i : (E - 1);
  const int d = edst[ic];
  const int lane = threadIdx.x & 63;
  const int d0 = __shfl(d, 0);
  if (__all(d == d0)) {
    const unsigned long long m = __ballot(valid);
    int base = 0;
    if (lane == 0) base = atomicAdd(&ccnt[d0], __popcll(m));
    base = __shfl(base, 0);
    if (valid) {
      const int pos = offs[d0] + base + __popcll(m & ((1ull << lane) - 1ull));
      csrc[pos] = esrc[ic];
      ceid[pos] = ic;
    }
  } else if (valid) {
    const int pos = offs[d] + atomicAdd(&ccnt[d], 1);
    csrc[pos] = esrc[ic];
    ceid[pos] = ic;
  }
}
__global__ void k_biglist(const int* __restrict__ offs, int* __restrict__ nbig,
                          int* __restrict__ big, int* __restrict__ bigoff) {
  for (int d = threadIdx.x; d < NT; d += 256) {
    const int dg = offs[d + 1] - offs[d];
    if (dg > 64) {
      const int idx = atomicAdd(nbig, 1);
      if (idx < 64) big[idx] = d;
    }
  }
  __syncthreads();
  if (threadIdx.x == 0) {
    int nb = *nbig; if (nb > 64) nb = 64;
    *nbig = nb;
    int o = 0;
    for (int i = 0; i < nb; ++i) {
      bigoff[i] = o;
      const int d = big[i];
      o += (offs[d + 1] - offs[d] + 255) / 256;
    }
    bigoff[nb] = o;
    bigoff[65] = o;
  }
}

// ---------------- aggregation ----------------
__global__ __launch_bounds__(256) void k_agg_small(
    const float* __restrict__ xw, const float* __restrict__ p, const float* __restrict__ z,
    const int* __restrict__ offs, const int* __restrict__ csrc, const int* __restrict__ ceid,
    const float* __restrict__ bias, float* __restrict__ out)
{
  const int d = blockIdx.x;
  const int cq = threadIdx.x << 2;
  const int o0 = offs[d], o1 = offs[d + 1];
  const float4 b4 = *(const float4*)(bias + cq);
  if (o1 - o0 > 64) {
    *(float4*)(out + (size_t)d * DHID + cq) = b4;
    return;
  }
  const int h = cq >> 8;
  const float zz = z[(size_t)d * 4 + h] + 1e-16f;
  float4 acc = make_float4(0.f, 0.f, 0.f, 0.f);
  for (int k = o0; k < o1; ++k) {
    const float pw = p[(size_t)ceid[k] * 4 + h];
    const float4 v = *(const float4*)(xw + (size_t)csrc[k] * DHID + cq);
    acc.x += pw * v.x; acc.y += pw * v.y; acc.z += pw * v.z; acc.w += pw * v.w;
  }
  uint4 r;
  r.x = packsplit(acc.x / zz + b4.x);
  r.y = packsplit(acc.y / zz + b4.y);
  r.z = packsplit(acc.z / zz + b4.z);
  r.w = packsplit(acc.w / zz + b4.w);
  *(uint4*)((unsigned*)out + (size_t)d * DHID + cq) = r;
}

__global__ __launch_bounds__(256) void k_agg_big(
    const float* __restrict__ xw, const float* __restrict__ p, const float* __restrict__ z,
    const int* __restrict__ offs, const int* __restrict__ csrc, const int* __restrict__ ceid,
    const int* __restrict__ nbig, const int* __restrict__ big, const int* __restrict__ bigoff,
    float* __restrict__ out)
{
  const int nb = *nbig;
  const int total = bigoff[65] * 4;
  for (int w = blockIdx.x; w < total; w += gridDim.x) {
    const int cg = w & 3;
    const int chunk = w >> 2;
    int bi = 0;
    while (bi + 1 < nb && bigoff[bi + 1] <= chunk) ++bi;
    const int node = big[bi];
    const int local = chunk - bigoff[bi];
    const int e0 = offs[node] + local * 256;
    int e1 = offs[node + 1];
    if (e1 > e0 + 256) e1 = e0 + 256;
    const int c = cg * 256 + threadIdx.x;
    float acc = 0.f;
    for (int k = e0; k < e1; ++k)
      acc += p[(size_t)ceid[k] * 4 + cg] * xw[(size_t)csrc[k] * DHID + c];
    const float zz = z[(size_t)node * 4 + cg] + 1e-16f;
    atomicAdd(&out[(size_t)node * DHID + c], acc / zz);
  }
}

// ---------------- head mean (uint4 x4 loads, float4 store) ----------------
__global__ __launch_bounds__(256) void k_head_mean(const float* __restrict__ h, float* __restrict__ out) {
  const size_t gid = (size_t)blockIdx.x * 256 + threadIdx.x;   // NT*64 threads
  if (gid >= (size_t)NT * 64) return;
  const int n = (int)(gid >> 6);
  const int dq = (int)(gid & 63) << 2;
  const unsigned* r = (const unsigned*)h + (size_t)n * DHID + dq;
  const uint4 r0 = *(const uint4*)(r + 0);
  const uint4 r1 = *(const uint4*)(r + 256);
  const uint4 r2 = *(const uint4*)(r + 512);
  const uint4 r3 = *(const uint4*)(r + 768);
  float4 o;
  o.x = (unpk(r0.x) + unpk(r1.x) + unpk(r2.x) + unpk(r3.x)) * 0.25f;
  o.y = (unpk(r0.y) + unpk(r1.y) + unpk(r2.y) + unpk(r3.y)) * 0.25f;
  o.z = (unpk(r0.z) + unpk(r1.z) + unpk(r2.z) + unpk(r3.z)) * 0.25f;
  o.w = (unpk(r0.w) + unpk(r1.w) + unpk(r2.w) + unpk(r3.w)) * 0.25f;
  *(float4*)(out + (size_t)n * DMOD + dq) = o;
}

__global__ void k_sentinel(float* out) { out[0] = 12345.0f; }

// ---------------- launcher ----------------
extern "C" void kernel_launch(void* const* d_in, const int* in_sizes, int n_in,
                              void* d_out, int out_size, void* d_ws, size_t ws_size,
                              hipStream_t stream) {
  const float* fv  = (const float*)d_in[0];
  const float* fa  = (const float*)d_in[1];
  const float* ft  = (const float*)d_in[2];
  const float* Wv  = (const float*)d_in[3];
  const float* bv  = (const float*)d_in[4];
  const float* Wa  = (const float*)d_in[5];
  const float* ba  = (const float*)d_in[6];
  const float* Wt  = (const float*)d_in[7];
  const float* bt  = (const float*)d_in[8];
  const float* mtok= (const float*)d_in[9];
  const float* gW  = (const float*)d_in[10];
  const float* gb  = (const float*)d_in[11];
  const float* eW1 = (const float*)d_in[12];
  const float* eb1 = (const float*)d_in[13];
  const float* eg  = (const float*)d_in[14];
  const float* ebt = (const float*)d_in[15];
  const float* eW2 = (const float*)d_in[16];
  const float* eb2 = (const float*)d_in[17];
  const float* gv  = (const float*)d_in[18];
  const float* gatW[3]  = {(const float*)d_in[19], (const float*)d_in[23], (const float*)d_in[27]};
  const float* gatAS[3] = {(const float*)d_in[20], (const float*)d_in[24], (const float*)d_in[28]};
  const float* gatAD[3] = {(const float*)d_in[21], (const float*)d_in[25], (const float*)d_in[29]};
  const float* gatB[3]  = {(const float*)d_in[22], (const float*)d_in[26], (const float*)d_in[30]};
  const void* maskraw = d_in[31];
  const int* esrc = (const int*)d_in[32];
  const int* edst = (const int*)d_in[33];
  const int E = in_sizes[32];

  if (ws_size < WSNEED) { k_sentinel<<<1, 1, 0, stream>>>((float*)d_out); return; }

  char* ws = (char*)d_ws;
  float* hA   = (float*)(ws + oA);
  float* hB   = (float*)(ws + oB);
  float* sS   = (float*)(ws + oSS);
  float* sD   = (float*)(ws + oSD);
  float* z    = (float*)(ws + oZ);
  float* p    = (float*)(ws + oP);
  float* tw   = (float*)(ws + oTW);
  int*   ti   = (int*)(ws + oTI);
  int*   plist= (int*)(ws + oPL);
  int*   pexp = (int*)(ws + oPE);
  float* ptw  = (float*)(ws + oPW);
  int*   deg  = (int*)(ws + oDG);
  int*   offs = (int*)(ws + oOF);
  int*   ccnt = (int*)(ws + oCC);
  int*   csrc = (int*)(ws + oCS);
  int*   ceid = (int*)(ws + oCE);
  int*   zsm  = (int*)(ws + oZS);
  int*   offs9= (int*)(ws + o9);
  int*   big  = (int*)(ws + oBG);
  int*   bigoff=(int*)(ws + oBO);
  int*   wsmask=(int*)(ws + oMK);
  double* Wc  = (double*)(ws + oWC);
  unsigned short* PBh = (unsigned short*)(ws + oPBh);
  unsigned short* PBl = (unsigned short*)(ws + oPBl);
  unsigned short* G0h = (unsigned short*)(ws + oG0h);
  unsigned short* G0l = (unsigned short*)(ws + oG0l);
  unsigned short* G1h = (unsigned short*)(ws + oG1h);
  unsigned short* G1l = (unsigned short*)(ws + oG1l);
  unsigned short* G2h = (unsigned short*)(ws + oG2h);
  unsigned short* G2l = (unsigned short*)(ws + oG2l);
  unsigned short* E1h = (unsigned short*)(ws + oE1h);
  unsigned short* E1l = (unsigned short*)(ws + oE1l);
  unsigned short* E2h = (unsigned short*)(ws + oE2h);
  unsigned short* E2l = (unsigned short*)(ws + oE2l);
  int*   flags = (int*)(ws + oFL);
  float* gWt   = (float*)(ws + oGWT);
  unsigned short* Gh[3] = {G0h, G1h, G2h};
  unsigned short* Gl_[3] = {G0l, G1l, G2l};
  float* x = (float*)d_out;   // packed proj output lives in d_out until final write

  const int eblk = (E + 255) / 256;

  // zero per-call state (zsm covers counts/cnt2/nbig/maskflag/nflag)
  hipMemsetAsync(zsm, 0, 256, stream);
  hipMemsetAsync(deg, 0, (size_t)(NT + 3) * 4, stream);
  hipMemsetAsync(ccnt, 0, (size_t)(NT + 3) * 4, stream);

  // mask canonicalization
  k_mask_flag<<<64, 256, 0, stream>>>((const unsigned int*)maskraw, zsm + 17);
  k_mask_canon<<<NV / 256, 256, 0, stream>>>(maskraw, zsm + 17, wsmask);

  // 0) weight transposes + bf16 splits (fragment-major global layout)
  k_tsplit<<<dim3(16, 4, 1), 256, 0, stream>>>(Wv, 1024, 256, 2304, 0,    0, 0, PBh, PBl);
  k_tsplit<<<dim3(8,  4, 1), 256, 0, stream>>>(Wa, 512,  256, 2304, 1024, 0, 0, PBh, PBl);
  k_tsplit<<<dim3(12, 4, 1), 256, 0, stream>>>(Wt, 768,  256, 2304, 1536, 0, 0, PBh, PBl);
  k_tsplit<<<dim3(4, 16, 1), 256, 0, stream>>>(gatW[0], 256, 1024, 256, 0, 0, 0, G0h, G0l);
  k_tsplit<<<dim3(16,16, 1), 256, 0, stream>>>(gatW[1], 1024, 1024, 1024, 0, 0, 0, G1h, G1l);
  k_tsplit<<<dim3(16,16, 1), 256, 0, stream>>>(gatW[2], 1024, 1024, 1024, 0, 0, 0, G2h, G2l);
  k_tsplit<<<dim3(4, 4, 8),  256, 0, stream>>>(eW1, 256, 256, 256, 0, 65536, 65536, E1h, E1l);
  k_tsplit<<<dim3(4, 4, 8),  256, 0, stream>>>(eW2, 256, 256, 256, 0, 65536, 65536, E2h, E2l);

  // 1) modal projection (+bias)/3 + mask token  -> x (PACKED, fused in epilogue)
  gemm_m<1><<<dim3(2, 512), 256, 0, stream>>>(
      NV, 2304, fv, 1024, fa, 512, ft, 768,
      PBh, PBl, 0, x, DMOD,
      bv, wsmask, mtok, ba, bt,
      nullptr, nullptr, nullptr, nullptr);

  // 2) MoE: fast f32 gate from packed x + f64 fix for near-ties, then sparse expert GEMMs
  k_wc<<<2306, 64, 0, stream>>>(Wv, Wa, Wt, bv, ba, bt, mtok, gW, gb, Wc);
  k_gwt<<<8, 256, 0, stream>>>(gW, gWt);
  k_gate_f32<<<NV / 4, 256, 0, stream>>>((const unsigned*)x, gWt, gb, Wc, wsmask,
                                         tw, ti, flags, zsm + 18);
  k_gate_fix<<<64, 256, 0, stream>>>(fv, fa, ft, Wc, wsmask, flags, zsm + 18, tw, ti);
  k_count<<<NV / 256, 256, 0, stream>>>(ti, zsm);
  k_moe_offs<<<1, 64, 0, stream>>>(zsm, offs9);
  k_moe_fill<<<CAPR / 256, 256, 0, stream>>>(offs9, plist, pexp);
  k_moe_scatter<<<NV / 256, 256, 0, stream>>>(ti, tw, offs9, zsm + 8, plist, ptw);
  gemm_m<2><<<dim3(2, CAPR / 128), 256, 0, stream>>>(
      CAPR, DMOD, nullptr, 0, nullptr, 0, nullptr, 0,
      E1h, E1l, (long)DMOD * DMOD, hB, DMOD,
      eb1, nullptr, nullptr, nullptr, nullptr,
      plist, pexp, nullptr, x);
  k_ln_gelu<<<CAPR, 256, 0, stream>>>(hB, plist, pexp, eg, ebt);   // writes packed
  hipMemsetAsync(hA, 0, (size_t)NT * DMOD * 4, stream);
  k_set_global<<<1, 256, 0, stream>>>(hA, gv);
  gemm_m<3><<<dim3(2, CAPR / 128), 256, 0, stream>>>(
      CAPR, DMOD, hB, DMOD, nullptr, 0, nullptr, 0,
      E2h, E2l, (long)DMOD * DMOD, hA, DMOD,
      eb2, nullptr, nullptr, nullptr, nullptr,
      plist, pexp, ptw, nullptr);
  // pack layer-0 h (f32 atomics above) -> packed for GEMM0
  k_pack<<<(int)(((size_t)NT * DMOD / 4 + 255) / 256), 256, 0, stream>>>(hA, (size_t)NT * DMOD);

  // 3) CSR (edges identical for all layers)
  k_deg<<<eblk, 256, 0, stream>>>(edst, deg, E);
  k_scan<<<1, 1024, 0, stream>>>(deg, offs);
  k_csr_scatter<<<eblk, 256, 0, stream>>>(esrc, edst, offs, ccnt, csrc, ceid, E);
  k_biglist<<<1, 256, 0, stream>>>(offs, zsm + 16, big, bigoff);

  // 4) 3 GAT layers: GEMM xw (hB) -> attention -> aggregate (packed) back into hA
  for (int l = 0; l < 3; ++l) {
    const int kin = (l == 0) ? DMOD : DHID;
    gemm_w<<<4104, 256, 0, stream>>>(
        NT, kin, (const unsigned*)hA, Gh[l], Gl_[l], hB, DHID);
    k_attn_s<<<(NT + 3) / 4, 256, 0, stream>>>(hB, gatAS[l], gatAD[l], sS, sD);
    hipMemsetAsync(z, 0, nf4, stream);
    k_edge_z<<<eblk, 256, 0, stream>>>(esrc, edst, sS, sD, p, z, E);
    k_agg_small<<<NT, 256, 0, stream>>>(hB, p, z, offs, csrc, ceid, gatB[l], hA);
    k_agg_big<<<4096, 256, 0, stream>>>(hB, p, z, offs, csrc, ceid, zsm + 16, big, bigoff, hA);
    k_pack_rows<<<64, 256, 0, stream>>>(hA, zsm + 16, big);
  }

  // 5) mean over heads (unpack hi+lo) -> d_out
  k_head_mean<<<(int)(((size_t)NT * 64 + 255) / 256), 256, 0, stream>>>(hA, (float*)d_out);
}

// Round 18
// 3399.316 us; speedup vs baseline: 1.1239x; 1.1239x over previous
//
#include <hip/hip_runtime.h>
#include <math.h>

// ---------------- problem constants ----------------
#define NV 65536              // conversation nodes
#define NT 65537              // + global vertex
#define DMOD 256              // hidden dim
#define DHID 1024             // HEADS * D
#define NEXPERT 8
#define CAPR (2*NV + NEXPERT*128)   // 132096 packed MoE rows (128-aligned buckets)
#define EMX 262208                  // >= actual edge count 262143

typedef __attribute__((ext_vector_type(4))) float f32x4;
typedef __attribute__((ext_vector_type(8))) short bf16x8;

// ---------------- ws layout (bytes) ----------------
static constexpr size_t kBig = (size_t)NT * DHID * sizeof(float);    // 268,439,552
static constexpr size_t oA   = 0;                // h buffer (h0 stride 256, later 1024)
static constexpr size_t oB   = kBig;             // xw / packed h1
static constexpr size_t nf4  = (size_t)NT * 16;  // NT x 4 floats
static constexpr size_t oSS  = 2*kBig;           // s_src
static constexpr size_t oSD  = oSS + nf4;        // s_dst
static constexpr size_t oZ   = oSD + nf4;        // z
static constexpr size_t oP   = oZ + nf4;         // p per edge (4 heads)
static constexpr size_t oTW  = oP  + (size_t)EMX*16;
static constexpr size_t oTI  = oTW + (size_t)NV*8;
static constexpr size_t oPL  = oTI + (size_t)NV*8;     // plist
static constexpr size_t oPE  = oPL + (size_t)CAPR*4;   // pexp
static constexpr size_t oPW  = oPE + (size_t)CAPR*4;   // ptw
static constexpr size_t oDG  = oPW + (size_t)CAPR*4;   // deg
static constexpr size_t oOF  = oDG + (size_t)(NT+3)*4; // csr offsets (NT+1)
static constexpr size_t oCC  = oOF + (size_t)(NT+3)*4; // csr fill counters
static constexpr size_t oCS  = oCC + (size_t)(NT+3)*4; // csr src
static constexpr size_t oCE  = oCS + (size_t)EMX*4;    // csr edge idx
static constexpr size_t oZS  = oCE + (size_t)EMX*4;    // 64 ints: [0..7]cnt [8..15]cnt2 [16]nbig [17]maskflag [18]nflag
static constexpr size_t o9   = oZS + 256;              // 9 ints padded offsets
static constexpr size_t oBG  = o9  + 64;               // big node list (64)
static constexpr size_t oBO  = oBG + 256;              // bigoff (66)
static constexpr size_t oMK  = oBO + 512;              // canonical int mask (NV)
static constexpr size_t oWC  = oMK + (size_t)NV*4;     // f64 gate weights, expert-major [8][2306]
static constexpr size_t oPBh = oWC + (size_t)8*2306*8;
static constexpr size_t zPB  = (size_t)256*2304*2;
static constexpr size_t oPBl = oPBh + zPB;
static constexpr size_t zG0  = (size_t)1024*256*2;
static constexpr size_t oG0h = oPBl + zPB;
static constexpr size_t oG0l = oG0h + zG0;
static constexpr size_t zG   = (size_t)1024*1024*2;
static constexpr size_t oG1h = oG0l + zG0;
static constexpr size_t oG1l = oG1h + zG;
static constexpr size_t oG2h = oG1l + zG;
static constexpr size_t oG2l = oG2h + zG;
static constexpr size_t zE   = (size_t)8*256*256*2;
static constexpr size_t oE1h = oG2l + zG;
static constexpr size_t oE1l = oE1h + zE;
static constexpr size_t oE2h = oE1l + zE;
static constexpr size_t oE2l = oE2h + zE;
static constexpr size_t oFL  = oE2l + zE;              // flagged node list (NV ints)
static constexpr size_t oGWT = oFL + (size_t)NV*4;     // gate_W^T f32 [8][256]
static constexpr size_t WSNEED = oGWT + (size_t)8*256*4;

// ---------------- bf16 split helpers ----------------
__device__ __forceinline__ unsigned f2bf(float f) {
  union { float f; unsigned u; } c; c.f = f;
  const unsigned u = c.u;
  return (u + 0x7FFFu + ((u >> 16) & 1u)) >> 16;
}
__device__ __forceinline__ float bf2f(unsigned h) {
  union { unsigned u; float f; } c; c.u = h << 16;
  return c.f;
}
__device__ __forceinline__ unsigned packsplit(float f) {
  const unsigned h = f2bf(f);
  const unsigned l = f2bf(f - bf2f(h));
  return (h << 16) | l;
}
__device__ __forceinline__ float unpk(unsigned u) {
  return bf2f(u >> 16) + bf2f(u & 0xFFFFu);
}
__device__ __forceinline__ void split8(const float4& v0, const float4& v1, uint4& uh, uint4& ul) {
  const float f[8] = {v0.x, v0.y, v0.z, v0.w, v1.x, v1.y, v1.z, v1.w};
  unsigned h[8], l[8];
  #pragma unroll
  for (int q = 0; q < 8; ++q) {
    h[q] = f2bf(f[q]);
    l[q] = f2bf(f[q] - bf2f(h[q]));
  }
  uh = make_uint4(h[0] | (h[1] << 16), h[2] | (h[3] << 16), h[4] | (h[5] << 16), h[6] | (h[7] << 16));
  ul = make_uint4(l[0] | (l[1] << 16), l[2] | (l[3] << 16), l[4] | (l[5] << 16), l[6] | (l[7] << 16));
}
// unpack 8 packed u32 (hi16|lo16) -> hi-pairs / lo-pairs (same layout as split8)
__device__ __forceinline__ void unpack8(const uint4& u0, const uint4& u1, uint4& uh, uint4& ul) {
  uh.x = (u0.x >> 16) | (u0.y & 0xFFFF0000u);  ul.x = (u0.x & 0xFFFFu) | (u0.y << 16);
  uh.y = (u0.z >> 16) | (u0.w & 0xFFFF0000u);  ul.y = (u0.z & 0xFFFFu) | (u0.w << 16);
  uh.z = (u1.x >> 16) | (u1.y & 0xFFFF0000u);  ul.z = (u1.x & 0xFFFFu) | (u1.y << 16);
  uh.w = (u1.z >> 16) | (u1.w & 0xFFFF0000u);  ul.w = (u1.z & 0xFFFFu) | (u1.w << 16);
}

// ---------------- in-place f32 -> packed split-bf16 ----------------
__global__ __launch_bounds__(256) void k_pack(float* __restrict__ buf, size_t n) {
  const size_t i = ((size_t)blockIdx.x * 256 + threadIdx.x) * 4;
  if (i >= n) return;
  float4 v = *(float4*)(buf + i);
  uint4 r;
  r.x = packsplit(v.x); r.y = packsplit(v.y); r.z = packsplit(v.z); r.w = packsplit(v.w);
  *(uint4*)(buf + i) = r;
}
// pack just the big-node rows (after agg_big's f32 atomics)
__global__ __launch_bounds__(256) void k_pack_rows(float* __restrict__ hA,
                                                  const int* __restrict__ nbig,
                                                  const int* __restrict__ big) {
  const int nb = *nbig;
  for (int bi = blockIdx.x; bi < nb; bi += gridDim.x) {
    const int node = big[bi];
    float* row = hA + (size_t)node * DHID;
    for (int c = threadIdx.x; c < DHID; c += 256)
      ((unsigned*)row)[c] = packsplit(row[c]);
  }
}

// ---------------- weight transpose + bf16-split -> FRAGMENT-MAJOR global layout ----------
// out layout (shorts): off = ((n>>4)*(Kout/8) + (k>>3))*128 + (n&15)*8 + (k&7)
__global__ __launch_bounds__(256) void k_tsplit(
    const float* __restrict__ in, int Kin, int Nin, int Kout, int koff,
    long ibstride, long obstride,
    unsigned short* __restrict__ oh, unsigned short* __restrict__ ol)
{
  __shared__ float t[64][68];
  const int b = blockIdx.z;
  in += (size_t)b * ibstride;
  oh += (size_t)b * obstride;
  ol += (size_t)b * obstride;
  const int k0 = blockIdx.x << 6, n0 = blockIdx.y << 6;
  const int tid = threadIdx.x;
  #pragma unroll
  for (int p = 0; p < 4; ++p) {
    const int r = (tid >> 4) + (p << 4);
    const int c4 = (tid & 15) << 2;
    *(float4*)&t[r][c4] = *(const float4*)(in + (size_t)(k0 + r) * Nin + n0 + c4);
  }
  __syncthreads();
  #pragma unroll
  for (int p = 0; p < 4; ++p) {
    const int n = n0 + (tid >> 4) + (p << 4);
    const int k4 = (tid & 15) << 2;
    unsigned h[4], l[4];
    #pragma unroll
    for (int q = 0; q < 4; ++q) {
      const float f = t[k4 + q][n - n0];
      h[q] = f2bf(f);
      l[q] = f2bf(f - bf2f(h[q]));
    }
    const int kg = koff + k0 + k4;
    const size_t off = ((size_t)(n >> 4) * (Kout >> 3) + (kg >> 3)) * 128 + (n & 15) * 8 + (kg & 7);
    *(uint2*)(oh + off) = make_uint2(h[0] | (h[1] << 16), h[2] | (h[3] << 16));
    *(uint2*)(ol + off) = make_uint2(l[0] | (l[1] << 16), l[2] | (l[3] << 16));
  }
}

// ---------------- split-bf16 MFMA GEMM (128x128 tile, 4 waves, 16x16x32) ----------------
// Double-buffered A staging (ONE barrier per k-tile). B fragments load DIRECTLY from
// global (fragment-major layout, 1KB sequential per read, L2-hot).
// MODE 0: packed A (hA); XCD-swizzled 1-D grid (8 n x 513 m)
// MODE 1: proj (3 K-segment f32 A + split8); epilogue writes PACKED x
// MODE 2: MoE W1 (gather PACKED A rows via plist; per-expert B/bias)
// MODE 3: MoE W2 (packed A=hB; per-expert B/bias; ptw-scaled f32 atomic scatter-add)
template<int MODE>
__global__ __launch_bounds__(256) void gemm_m(
    int M, int K,
    const float* __restrict__ A0, int lda0,
    const float* __restrict__ A1, int lda1,
    const float* __restrict__ A2, int lda2,
    const unsigned short* __restrict__ BTh, const unsigned short* __restrict__ BTl,
    long bstride,
    float* __restrict__ C, int ldc,
    const float* __restrict__ bias0,
    const int* __restrict__ mask, const float* __restrict__ mtok,
    const float* __restrict__ biasx1, const float* __restrict__ biasx2,
    const int* __restrict__ plist, const int* __restrict__ pexp, const float* __restrict__ ptw,
    const float* __restrict__ gsrc)
{
  __shared__ uint4 AshF[2][512];
  __shared__ uint4 AslF[2][512];
  const int tid = threadIdx.x;
  int bn0, bm0;
  if (MODE == 0) {
    const int b = blockIdx.x;
    const int t = (b & 7) * 513 + (b >> 3);
    bn0 = (t & 7) << 7;
    bm0 = (t >> 3) << 7;
  } else {
    bn0 = blockIdx.x << 7;
    bm0 = blockIdx.y << 7;
  }
  int eb = 0;
  if (MODE == 2 || MODE == 3) eb = pexp[bm0];
  const int wid = tid >> 6, lane = tid & 63;
  const int wm = wid >> 1, wn = wid & 1;
  const int l15 = lane & 15, lg = lane >> 4;
  f32x4 acc[4][4];
  #pragma unroll
  for (int i = 0; i < 4; ++i)
    #pragma unroll
    for (int j = 0; j < 4; ++j) acc[i][j] = (f32x4)0.f;

  const int srow = tid >> 2;
  const int lgw  = tid & 3;
  const int k8 = lgw << 3;
  const size_t nfrow = (size_t)K * 2;
  const uint4* bph = (const uint4*)(BTh + (size_t)eb * bstride)
                     + (size_t)((bn0 >> 4) + (wn << 2)) * nfrow + lane;
  const uint4* bpl = (const uint4*)(BTl + (size_t)eb * bstride)
                     + (size_t)((bn0 >> 4) + (wn << 2)) * nfrow + lane;
  const int ridx = lane ^ lg;
  int nodes[2] = {0, 0};
  if (MODE == 2) {
    nodes[0] = plist[bm0 + srow];
    nodes[1] = plist[bm0 + srow + 64];
  }
  const int nkt = K >> 5;
  uint4 su0[2], su1[2];
  float4 sv0[2], sv1[2];

  auto loadA = [&](int kt) {
    const int kk = (kt << 5) + k8;
    #pragma unroll
    for (int p = 0; p < 2; ++p) {
      const int grow = bm0 + srow + (p << 6);
      if (MODE == 1) {
        const float* ap; int kloc;
        if (kk < 1024)      { ap = A0 + (size_t)grow * lda0; kloc = kk; }
        else if (kk < 1536) { ap = A1 + (size_t)grow * lda1; kloc = kk - 1024; }
        else                { ap = A2 + (size_t)grow * lda2; kloc = kk - 1536; }
        sv0[p] = *(const float4*)(ap + kloc);
        sv1[p] = *(const float4*)(ap + kloc + 4);
      } else if (MODE == 2) {
        const int nd = nodes[p];
        su0[p] = make_uint4(0, 0, 0, 0); su1[p] = su0[p];
        if (nd >= 0) {
          const unsigned* ap = (const unsigned*)gsrc + (size_t)nd * DMOD + kk;
          su0[p] = *(const uint4*)ap; su1[p] = *(const uint4*)(ap + 4);
        }
      } else {
        su0[p] = make_uint4(0, 0, 0, 0); su1[p] = su0[p];
        if (MODE == 3 || grow < M) {
          const unsigned* ap = (const unsigned*)A0 + (size_t)grow * lda0 + kk;
          su0[p] = *(const uint4*)ap; su1[p] = *(const uint4*)(ap + 4);
        }
      }
    }
  };
  auto storeA = [&](int buf) {
    #pragma unroll
    for (int p = 0; p < 2; ++p) {
      uint4 uh, ul;
      if (MODE == 1) split8(sv0[p], sv1[p], uh, ul);
      else           unpack8(su0[p], su1[p], uh, ul);
      const int r = srow + (p << 6);
      const int wi = ((r >> 4) << 6) + (lgw << 4) + ((r & 15) ^ lgw);
      AshF[buf][wi] = uh;
      AslF[buf][wi] = ul;
    }
  };

  loadA(0);
  storeA(0);
  __syncthreads();
  for (int kt = 0; kt < nkt; ++kt) {
    const int cur = kt & 1;
    bf16x8 bh[4], bl[4];
    #pragma unroll
    for (int j = 0; j < 4; ++j) {
      bh[j] = *(const bf16x8*)(bph + (size_t)j * nfrow + (kt << 6));
      bl[j] = *(const bf16x8*)(bpl + (size_t)j * nfrow + (kt << 6));
    }
    bf16x8 ah[4], al[4];
    #pragma unroll
    for (int i = 0; i < 4; ++i) {
      ah[i] = ((const bf16x8*)AshF[cur])[(((wm << 2) + i) << 6) + ridx];
      al[i] = ((const bf16x8*)AslF[cur])[(((wm << 2) + i) << 6) + ridx];
    }
    if (kt + 1 < nkt) loadA(kt + 1);
    #pragma unroll
    for (int i = 0; i < 4; ++i)
      #pragma unroll
      for (int j = 0; j < 4; ++j) {
        f32x4 t = acc[i][j];
        t = __builtin_amdgcn_mfma_f32_16x16x32_bf16(al[i], bh[j], t, 0, 0, 0);
        t = __builtin_amdgcn_mfma_f32_16x16x32_bf16(ah[i], bl[j], t, 0, 0, 0);
        t = __builtin_amdgcn_mfma_f32_16x16x32_bf16(ah[i], bh[j], t, 0, 0, 0);
        acc[i][j] = t;
      }
    if (kt + 1 < nkt) storeA(cur ^ 1);
    __syncthreads();
  }
  // ---- epilogue (C/D map: col = lane&15, row = (lane>>4)*4 + reg) ----
  const int r0 = bm0 + (wm << 6), c0 = bn0 + (wn << 6);
  #pragma unroll
  for (int i = 0; i < 4; ++i) {
    #pragma unroll
    for (int v = 0; v < 4; ++v) {
      const int r = r0 + (i << 4) + (lg << 2) + v;
      if ((MODE == 0) && r >= M) continue;
      int node = 0; float pw = 0.f; int msk = 0;
      if (MODE == 3) { node = plist[r]; if (node < 0) continue; pw = ptw[r]; }
      if (MODE == 1) msk = mask[r];
      #pragma unroll
      for (int j = 0; j < 4; ++j) {
        const int c = c0 + (j << 4) + l15;
        const float a = acc[i][j][v];
        if (MODE == 0) {
          C[(size_t)r * ldc + c] = a;
        } else if (MODE == 1) {
          float val = (a + bias0[c] + biasx1[c] + biasx2[c]) * (1.f / 3.f);
          if (msk) val = mtok[c];
          ((unsigned*)C)[(size_t)r * ldc + c] = packsplit(val);
        } else if (MODE == 2) {
          C[(size_t)r * ldc + c] = a + bias0[eb * DMOD + c];
        } else {
          atomicAdd(C + (size_t)node * DMOD + c, (a + bias0[eb * DMOD + c]) * pw);
        }
      }
    }
  }
}

// ---------------- mask dtype detect + canonicalize ----------------
__global__ void k_mask_flag(const unsigned int* __restrict__ mw, int* __restrict__ flag) {
  const int i = blockIdx.x * 256 + threadIdx.x;
  if (i < 16384 && (mw[i] & 0xFFFFFF00u)) atomicOr(flag, 1);
}
__global__ void k_mask_canon(const void* __restrict__ m, const int* __restrict__ flag, int* __restrict__ out) {
  const int i = blockIdx.x * 256 + threadIdx.x;
  if (i >= NV) return;
  out[i] = (*flag) ? (int)((const unsigned char*)m)[i] : ((const int*)m)[i];
}

// ---------------- f64-true gate weights, EXPERT-MAJOR: Wc[e][2306] ----------------
__global__ __launch_bounds__(64) void k_wc(
    const float* __restrict__ Wv, const float* __restrict__ Wa, const float* __restrict__ Wt,
    const float* __restrict__ bv, const float* __restrict__ ba, const float* __restrict__ bt,
    const float* __restrict__ mtok, const float* __restrict__ gW, const float* __restrict__ gb,
    double* __restrict__ Wc)
{
  const int r = blockIdx.x;
  const int l = threadIdx.x;
  float4 w;
  if (r < 1024)       w = *(const float4*)(Wv + (size_t)r * DMOD + l * 4);
  else if (r < 1536)  w = *(const float4*)(Wa + (size_t)(r - 1024) * DMOD + l * 4);
  else if (r < 2304)  w = *(const float4*)(Wt + (size_t)(r - 1536) * DMOD + l * 4);
  else if (r == 2304) {
    const float4 b0 = *(const float4*)(bv + l * 4);
    const float4 b1 = *(const float4*)(ba + l * 4);
    const float4 b2 = *(const float4*)(bt + l * 4);
    w = make_float4(b0.x + b1.x + b2.x, b0.y + b1.y + b2.y, b0.z + b1.z + b2.z, b0.w + b1.w + b2.w);
  } else              w = *(const float4*)(mtok + l * 4);
  const float wq[4] = {w.x, w.y, w.z, w.w};
  double acc[NEXPERT];
  #pragma unroll
  for (int e = 0; e < NEXPERT; ++e) acc[e] = 0.0;
  #pragma unroll
  for (int q = 0; q < 4; ++q) {
    const int d = l * 4 + q;
    #pragma unroll
    for (int e = 0; e < NEXPERT; ++e)
      acc[e] += (double)wq[q] * (double)gW[d * NEXPERT + e];
  }
  #pragma unroll
  for (int e = 0; e < NEXPERT; ++e) {
    #pragma unroll
    for (int o = 32; o > 0; o >>= 1) acc[e] += __shfl_xor(acc[e], o);
  }
  if (l == 0) {
    const double s = (r <= 2304) ? (1.0 / 3.0) : 1.0;
    #pragma unroll
    for (int e = 0; e < NEXPERT; ++e) {
      double v = acc[e] * s;
      if (r >= 2304) v += (double)gb[e];
      Wc[(size_t)e * 2306 + r] = v;
    }
  }
}

// ---------------- gate_W^T f32 [8][256] ----------------
__global__ void k_gwt(const float* __restrict__ gW, float* __restrict__ gWt) {
  const int i = blockIdx.x * 256 + threadIdx.x;   // i = e*256 + d
  if (i >= 8 * 256) return;
  const int e = i >> 8, d = i & 255;
  gWt[i] = gW[d * NEXPERT + e];
}

// ---------------- fast f32 gate from packed x; flag near-ties (2nd vs 3rd gap) ------------
__global__ __launch_bounds__(256) void k_gate_f32(
    const unsigned* __restrict__ xp, const float* __restrict__ gWt, const float* __restrict__ gb,
    const double* __restrict__ Wc, const int* __restrict__ mask,
    float* __restrict__ tw, int* __restrict__ ti,
    int* __restrict__ flags, int* __restrict__ nflag)
{
  const int wv = (blockIdx.x * 256 + threadIdx.x) >> 6;
  const int lane = threadIdx.x & 63;
  if (wv >= NV) return;
  const int msk = mask[wv];
  float acc[NEXPERT];
  #pragma unroll
  for (int e = 0; e < NEXPERT; ++e) acc[e] = 0.f;
  if (!msk) {
    const uint4 u = *(const uint4*)(xp + (size_t)wv * DMOD + lane * 4);
    const float xv[4] = {unpk(u.x), unpk(u.y), unpk(u.z), unpk(u.w)};
    #pragma unroll
    for (int e = 0; e < NEXPERT; ++e) {
      const float4 w = *(const float4*)(gWt + e * DMOD + lane * 4);
      acc[e] = xv[0] * w.x + xv[1] * w.y + xv[2] * w.z + xv[3] * w.w;
    }
    #pragma unroll
    for (int e = 0; e < NEXPERT; ++e) {
      #pragma unroll
      for (int o = 32; o > 0; o >>= 1) acc[e] += __shfl_xor(acc[e], o);
    }
  }
  if (lane == 0) {
    float le[NEXPERT];
    #pragma unroll
    for (int e = 0; e < NEXPERT; ++e)
      le[e] = msk ? (float)Wc[(size_t)e * 2306 + 2305] : (acc[e] + gb[e]);
    int b0 = -1, b1 = -1;
    float v0 = -1e30f, v1 = -1e30f, v2 = -1e30f;
    #pragma unroll
    for (int e = 0; e < NEXPERT; ++e) {
      const float v = le[e];
      if (v > v0)      { v2 = v1; v1 = v0; b1 = b0; v0 = v; b0 = e; }
      else if (v > v1) { v2 = v1; v1 = v; b1 = e; }
      else if (v > v2) { v2 = v; }
    }
    const double w0 = 1.0 / (1.0 + exp((double)v1 - (double)v0));
    tw[wv * 2 + 0] = (float)w0;
    tw[wv * 2 + 1] = (float)(1.0 - w0);
    ti[wv * 2 + 0] = b0;
    ti[wv * 2 + 1] = b1;
    if (v1 - v2 < 1e-3f) {
      const int idx = atomicAdd(nflag, 1);
      if (idx < NV) flags[idx] = wv;
    }
  }
}

// ---------------- f64 exact gate for flagged nodes ----------------
__global__ __launch_bounds__(256) void k_gate_fix(
    const float* __restrict__ fv, const float* __restrict__ fa, const float* __restrict__ ft,
    const double* __restrict__ Wc, const int* __restrict__ mask,
    const int* __restrict__ flags, const int* __restrict__ nflag,
    float* __restrict__ tw, int* __restrict__ ti)
{
  int nf = *nflag; if (nf > NV) nf = NV;
  const int lane = threadIdx.x & 63;
  const int wix = (blockIdx.x * 256 + threadIdx.x) >> 6;
  const int nw = gridDim.x * 4;
  for (int idx = wix; idx < nf; idx += nw) {
    const int node = flags[idx];
    const int msk = mask[node];
    double acc[NEXPERT];
    #pragma unroll
    for (int e = 0; e < NEXPERT; ++e) acc[e] = 0.0;
    if (!msk) {
      #pragma unroll
      for (int c = 0; c < 9; ++c) {
        const int kg0 = c * 256 + lane * 4;
        const float* base; int kloc;
        if (kg0 < 1024)      { base = fv + (size_t)node * 1024; kloc = kg0; }
        else if (kg0 < 1536) { base = fa + (size_t)node * 512;  kloc = kg0 - 1024; }
        else                 { base = ft + (size_t)node * 768;  kloc = kg0 - 1536; }
        const float4 f = *(const float4*)(base + kloc);
        const float fq[4] = {f.x, f.y, f.z, f.w};
        #pragma unroll
        for (int q = 0; q < 4; ++q) {
          #pragma unroll
          for (int e = 0; e < NEXPERT; ++e)
            acc[e] += (double)fq[q] * Wc[(size_t)e * 2306 + kg0 + q];
        }
      }
      #pragma unroll
      for (int e = 0; e < NEXPERT; ++e) {
        #pragma unroll
        for (int o = 32; o > 0; o >>= 1) acc[e] += __shfl_xor(acc[e], o);
      }
    }
    if (lane == 0) {
      double le[NEXPERT];
      #pragma unroll
      for (int e = 0; e < NEXPERT; ++e)
        le[e] = msk ? Wc[(size_t)e * 2306 + 2305] : (acc[e] + Wc[(size_t)e * 2306 + 2304]);
      int b0 = -1, b1 = -1;
      double v0 = -1e300, v1 = -1e300;
      for (int e = 0; e < NEXPERT; ++e) {
        if (le[e] > v0) { v1 = v0; b1 = b0; v0 = le[e]; b0 = e; }
        else if (le[e] > v1) { v1 = le[e]; b1 = e; }
      }
      const double w0 = 1.0 / (1.0 + exp(v1 - v0));
      tw[node * 2 + 0] = (float)w0;
      tw[node * 2 + 1] = (float)(1.0 - w0);
      ti[node * 2 + 0] = b0;
      ti[node * 2 + 1] = b1;
    }
  }
}

// ---------------- expert counts from final ti (block-aggregated) ----------------
__global__ __launch_bounds__(256) void k_count(const int* __restrict__ ti, int* __restrict__ counts) {
  __shared__ int lcnt[NEXPERT];
  const int tid = threadIdx.x;
  const int n = blockIdx.x * 256 + tid;
  if (tid < NEXPERT) lcnt[tid] = 0;
  __syncthreads();
  const int e0 = ti[n * 2 + 0];
  const int e1 = ti[n * 2 + 1];
  if ((unsigned)e0 < NEXPERT) atomicAdd(&lcnt[e0], 1);
  if ((unsigned)e1 < NEXPERT) atomicAdd(&lcnt[e1], 1);
  __syncthreads();
  if (tid < NEXPERT && lcnt[tid] > 0) atomicAdd(&counts[tid], lcnt[tid]);
}

__global__ void k_moe_offs(const int* __restrict__ counts, int* __restrict__ offs9) {
  if (threadIdx.x == 0 && blockIdx.x == 0) {
    int o = 0;
    for (int e = 0; e < NEXPERT; ++e) { offs9[e] = o; o += (counts[e] + 127) & ~127; }
    offs9[NEXPERT] = o;
  }
}
__global__ void k_moe_fill(const int* __restrict__ offs9, int* __restrict__ plist, int* __restrict__ pexp) {
  const int r = blockIdx.x * 256 + threadIdx.x;
  if (r >= CAPR) return;
  int e = 0;
  while (e < NEXPERT - 1 && r >= offs9[e + 1]) ++e;
  pexp[r] = e;
  plist[r] = -1;
}
__global__ __launch_bounds__(256) void k_moe_scatter(
    const int* __restrict__ ti, const float* __restrict__ tw,
    const int* __restrict__ offs9, int* __restrict__ cnt2,
    int* __restrict__ plist, float* __restrict__ ptw) {
  __shared__ int lcnt[NEXPERT];
  __shared__ int lbase[NEXPERT];
  const int tid = threadIdx.x;
  const int n = blockIdx.x * 256 + tid;
  if (tid < NEXPERT) lcnt[tid] = 0;
  __syncthreads();
  const int e0 = ti[n * 2 + 0];
  const int e1 = ti[n * 2 + 1];
  const bool v0 = (unsigned)e0 < NEXPERT;
  const bool v1 = (unsigned)e1 < NEXPERT;
  int r0 = 0, r1 = 0;
  if (v0) r0 = atomicAdd(&lcnt[e0], 1);
  if (v1) r1 = atomicAdd(&lcnt[e1], 1);
  __syncthreads();
  if (tid < NEXPERT && lcnt[tid] > 0) lbase[tid] = atomicAdd(&cnt2[tid], lcnt[tid]);
  __syncthreads();
  if (v0) {
    const int pos = offs9[e0] + lbase[e0] + r0;
    if ((unsigned)pos < CAPR) { plist[pos] = n; ptw[pos] = tw[n * 2 + 0]; }
  }
  if (v1) {
    const int pos = offs9[e1] + lbase[e1] + r1;
    if ((unsigned)pos < CAPR) { plist[pos] = n; ptw[pos] = tw[n * 2 + 1]; }
  }
}

// ---------------- LN + exact GELU on packed rows (writes PACKED split-bf16) ----------------
__global__ __launch_bounds__(256) void k_ln_gelu(
    float* __restrict__ h1, const int* __restrict__ plist, const int* __restrict__ pexp,
    const float* __restrict__ g, const float* __restrict__ beta)
{
  const int r = blockIdx.x;
  if (plist[r] < 0) return;
  const int e = pexp[r];
  const int t = threadIdx.x;
  __shared__ float red[4];
  __shared__ float bc;
  const float v = h1[(size_t)r * DMOD + t];
  float s = v;
  #pragma unroll
  for (int o = 32; o > 0; o >>= 1) s += __shfl_xor(s, o);
  if ((t & 63) == 0) red[t >> 6] = s;
  __syncthreads();
  if (t == 0) bc = (red[0] + red[1] + red[2] + red[3]) * (1.f / 256.f);
  __syncthreads();
  const float mu = bc;
  const float dv = v - mu;
  float s2 = dv * dv;
  #pragma unroll
  for (int o = 32; o > 0; o >>= 1) s2 += __shfl_xor(s2, o);
  __syncthreads();
  if ((t & 63) == 0) red[t >> 6] = s2;
  __syncthreads();
  if (t == 0) bc = (red[0] + red[1] + red[2] + red[3]) * (1.f / 256.f);
  __syncthreads();
  const float var = bc;
  const float y = dv * rsqrtf(var + 1e-5f) * g[e * DMOD + t] + beta[e * DMOD + t];
  const float gl = y * 0.5f * (1.f + erff(y * 0.70710678118654752f));
  ((unsigned*)h1)[(size_t)r * DMOD + t] = packsplit(gl);
}

__global__ void k_set_global(float* __restrict__ h0, const float* __restrict__ gv) {
  h0[(size_t)NV * DMOD + threadIdx.x] = gv[threadIdx.x];
}

// ---------------- GAT attention pieces ----------------
__global__ __launch_bounds__(256) void k_attn_s(
    const float* __restrict__ xw, const float* __restrict__ aS, const float* __restrict__ aD,
    float* __restrict__ sS, float* __restrict__ sD)
{
  const int wv = (blockIdx.x * 256 + threadIdx.x) >> 6;
  const int lane = threadIdx.x & 63;
  if (wv >= NT) return;
  const int h = lane >> 4, j = lane & 15;
  const float* row = xw + (size_t)wv * DHID + h * DMOD + j * 16;
  const float* av = aS + h * DMOD + j * 16;
  const float* dv = aD + h * DMOD + j * 16;
  float ps = 0.f, pd = 0.f;
  #pragma unroll
  for (int q = 0; q < 16; q += 4) {
    const float4 xv = *(const float4*)(row + q);
    const float4 a4 = *(const float4*)(av + q);
    const float4 d4 = *(const float4*)(dv + q);
    ps += xv.x * a4.x + xv.y * a4.y + xv.z * a4.z + xv.w * a4.w;
    pd += xv.x * d4.x + xv.y * d4.y + xv.z * d4.z + xv.w * d4.w;
  }
  #pragma unroll
  for (int o = 1; o <= 8; o <<= 1) { ps += __shfl_xor(ps, o); pd += __shfl_xor(pd, o); }
  if (j == 0) { sS[(size_t)wv * 4 + h] = ps; sD[(size_t)wv * 4 + h] = pd; }
}

__global__ __launch_bounds__(256) void k_edge_z(
    const int* __restrict__ esrc, const int* __restrict__ edst,
    const float* __restrict__ sS, const float* __restrict__ sD,
    float* __restrict__ p, float* __restrict__ z, int E)
{
  const int i = blockIdx.x * 256 + threadIdx.x;
  const bool valid = i < E;
  const int ic = valid ? i : (E - 1);
  const int dst = edst[ic];
  const int src = esrc[ic];
  const float4 a = *(const float4*)(sS + (size_t)src * 4);
  const float4 b = *(const float4*)(sD + (size_t)dst * 4);
  float e4[4] = {a.x + b.x, a.y + b.y, a.z + b.z, a.w + b.w};
  float pv[4];
  #pragma unroll
  for (int h = 0; h < 4; ++h) {
    const float e = e4[h] > 0.f ? e4[h] : 0.2f * e4[h];
    pv[h] = expf(e);
  }
  if (valid) *(float4*)(p + (size_t)i * 4) = make_float4(pv[0], pv[1], pv[2], pv[3]);
  float c4[4];
  #pragma unroll
  for (int h = 0; h < 4; ++h) c4[h] = valid ? pv[h] : 0.f;
  const int d0 = __shfl(dst, 0);
  if (__all(dst == d0)) {
    #pragma unroll
    for (int h = 0; h < 4; ++h) {
      #pragma unroll
      for (int o = 1; o <= 32; o <<= 1) c4[h] += __shfl_xor(c4[h], o);
    }
    if ((threadIdx.x & 63) == 0) {
      #pragma unroll
      for (int h = 0; h < 4; ++h) atomicAdd(&z[(size_t)d0 * 4 + h], c4[h]);
    }
  } else if (valid) {
    #pragma unroll
    for (int h = 0; h < 4; ++h) atomicAdd(&z[(size_t)dst * 4 + h], c4[h]);
  }
}

// ---------------- CSR build (wave-aggregated atomics for hot destinations) ----------------
__global__ void k_deg(const int* __restrict__ edst, int* __restrict__ deg, int E) {
  const int i = blockIdx.x * 256 + threadIdx.x;
  const bool valid = i < E;
  const int ic = valid ? i : (E - 1);
  const int d = edst[ic];
  const int d0 = __shfl(d, 0);
  if (__all(d == d0)) {
    const unsigned long long m = __ballot(valid);
    if ((threadIdx.x & 63) == 0) atomicAdd(&deg[d0], __popcll(m));
  } else if (valid) {
    atomicAdd(&deg[d], 1);
  }
}
__global__ __launch_bounds__(1024) void k_scan(const int* __restrict__ deg, int* __restrict__ offs) {
  __shared__ int part[1024];
  const int t = threadIdx.x;
  const int s0 = t * 65;
  int sum = 0;
  for (int j = 0; j < 65; ++j) { const int idx = s0 + j; if (idx < NT) sum += deg[idx]; }
  part[t] = sum;
  __syncthreads();
  for (int off = 1; off < 1024; off <<= 1) {
    const int v = (t >= off) ? part[t - off] : 0;
    __syncthreads();
    part[t] += v;
    __syncthreads();
  }
  int run = part[t] - sum;
  for (int j = 0; j < 65; ++j) {
    const int idx = s0 + j;
    if (idx < NT) { offs[idx] = run; run += deg[idx]; }
  }
  if (t == 1023) offs[NT] = part[1023];
}
__global__ void k_csr_scatter(const int* __restrict__ esrc, const int* __restrict__ edst,
                              const int* __restrict__ offs, int* __restrict__ ccnt,
                              int* __restrict__ csrc, int* __restrict__ ceid, int E) {
  const int i = blockIdx.x * 256 + threadIdx.x;
  const bool valid = i < E;
  const int ic = valid ? i : (E - 1);
  const int d = edst[ic];
  const int lane = threadIdx.x & 63;
  const int d0 = __shfl(d, 0);
  if (__all(d == d0)) {
    const unsigned long long m = __ballot(valid);
    int base = 0;
    if (lane == 0) base = atomicAdd(&ccnt[d0], __popcll(m));
    base = __shfl(base, 0);
    if (valid) {
      const int pos = offs[d0] + base + __popcll(m & ((1ull << lane) - 1ull));
      csrc[pos] = esrc[ic];
      ceid[pos] = ic;
    }
  } else if (valid) {
    const int pos = offs[d] + atomicAdd(&ccnt[d], 1);
    csrc[pos] = esrc[ic];
    ceid[pos] = ic;
  }
}
__global__ void k_biglist(const int* __restrict__ offs, int* __restrict__ nbig,
                          int* __restrict__ big, int* __restrict__ bigoff) {
  for (int d = threadIdx.x; d < NT; d += 256) {
    const int dg = offs[d + 1] - offs[d];
    if (dg > 64) {
      const int idx = atomicAdd(nbig, 1);
      if (idx < 64) big[idx] = d;
    }
  }
  __syncthreads();
  if (threadIdx.x == 0) {
    int nb = *nbig; if (nb > 64) nb = 64;
    *nbig = nb;
    int o = 0;
    for (int i = 0; i < nb; ++i) {
      bigoff[i] = o;
      const int d = big[i];
      o += (offs[d + 1] - offs[d] + 255) / 256;
    }
    bigoff[nb] = o;
    bigoff[65] = o;
  }
}

// ---------------- aggregation ----------------
__global__ __launch_bounds__(256) void k_agg_small(
    const float* __restrict__ xw, const float* __restrict__ p, const float* __restrict__ z,
    const int* __restrict__ offs, const int* __restrict__ csrc, const int* __restrict__ ceid,
    const float* __restrict__ bias, float* __restrict__ out)
{
  const int d = blockIdx.x;
  const int cq = threadIdx.x << 2;
  const int o0 = offs[d], o1 = offs[d + 1];
  const float4 b4 = *(const float4*)(bias + cq);
  if (o1 - o0 > 64) {
    *(float4*)(out + (size_t)d * DHID + cq) = b4;
    return;
  }
  const int h = cq >> 8;
  const float zz = z[(size_t)d * 4 + h] + 1e-16f;
  float4 acc = make_float4(0.f, 0.f, 0.f, 0.f);
  for (int k = o0; k < o1; ++k) {
    const float pw = p[(size_t)ceid[k] * 4 + h];
    const float4 v = *(const float4*)(xw + (size_t)csrc[k] * DHID + cq);
    acc.x += pw * v.x; acc.y += pw * v.y; acc.z += pw * v.z; acc.w += pw * v.w;
  }
  uint4 r;
  r.x = packsplit(acc.x / zz + b4.x);
  r.y = packsplit(acc.y / zz + b4.y);
  r.z = packsplit(acc.z / zz + b4.z);
  r.w = packsplit(acc.w / zz + b4.w);
  *(uint4*)((unsigned*)out + (size_t)d * DHID + cq) = r;
}

__global__ __launch_bounds__(256) void k_agg_big(
    const float* __restrict__ xw, const float* __restrict__ p, const float* __restrict__ z,
    const int* __restrict__ offs, const int* __restrict__ csrc, const int* __restrict__ ceid,
    const int* __restrict__ nbig, const int* __restrict__ big, const int* __restrict__ bigoff,
    float* __restrict__ out)
{
  const int nb = *nbig;
  const int total = bigoff[65] * 4;
  for (int w = blockIdx.x; w < total; w += gridDim.x) {
    const int cg = w & 3;
    const int chunk = w >> 2;
    int bi = 0;
    while (bi + 1 < nb && bigoff[bi + 1] <= chunk) ++bi;
    const int node = big[bi];
    const int local = chunk - bigoff[bi];
    const int e0 = offs[node] + local * 256;
    int e1 = offs[node + 1];
    if (e1 > e0 + 256) e1 = e0 + 256;
    const int c = cg * 256 + threadIdx.x;
    float acc = 0.f;
    for (int k = e0; k < e1; ++k)
      acc += p[(size_t)ceid[k] * 4 + cg] * xw[(size_t)csrc[k] * DHID + c];
    const float zz = z[(size_t)node * 4 + cg] + 1e-16f;
    atomicAdd(&out[(size_t)node * DHID + c], acc / zz);
  }
}

// ---------------- head mean (uint4 x4 loads, float4 store) ----------------
__global__ __launch_bounds__(256) void k_head_mean(const float* __restrict__ h, float* __restrict__ out) {
  const size_t gid = (size_t)blockIdx.x * 256 + threadIdx.x;   // NT*64 threads
  if (gid >= (size_t)NT * 64) return;
  const int n = (int)(gid >> 6);
  const int dq = (int)(gid & 63) << 2;
  const unsigned* r = (const unsigned*)h + (size_t)n * DHID + dq;
  const uint4 r0 = *(const uint4*)(r + 0);
  const uint4 r1 = *(const uint4*)(r + 256);
  const uint4 r2 = *(const uint4*)(r + 512);
  const uint4 r3 = *(const uint4*)(r + 768);
  float4 o;
  o.x = (unpk(r0.x) + unpk(r1.x) + unpk(r2.x) + unpk(r3.x)) * 0.25f;
  o.y = (unpk(r0.y) + unpk(r1.y) + unpk(r2.y) + unpk(r3.y)) * 0.25f;
  o.z = (unpk(r0.z) + unpk(r1.z) + unpk(r2.z) + unpk(r3.z)) * 0.25f;
  o.w = (unpk(r0.w) + unpk(r1.w) + unpk(r2.w) + unpk(r3.w)) * 0.25f;
  *(float4*)(out + (size_t)n * DMOD + dq) = o;
}

__global__ void k_sentinel(float* out) { out[0] = 12345.0f; }

// ---------------- launcher ----------------
extern "C" void kernel_launch(void* const* d_in, const int* in_sizes, int n_in,
                              void* d_out, int out_size, void* d_ws, size_t ws_size,
                              hipStream_t stream) {
  const float* fv  = (const float*)d_in[0];
  const float* fa  = (const float*)d_in[1];
  const float* ft  = (const float*)d_in[2];
  const float* Wv  = (const float*)d_in[3];
  const float* bv  = (const float*)d_in[4];
  const float* Wa  = (const float*)d_in[5];
  const float* ba  = (const float*)d_in[6];
  const float* Wt  = (const float*)d_in[7];
  const float* bt  = (const float*)d_in[8];
  const float* mtok= (const float*)d_in[9];
  const float* gW  = (const float*)d_in[10];
  const float* gb  = (const float*)d_in[11];
  const float* eW1 = (const float*)d_in[12];
  const float* eb1 = (const float*)d_in[13];
  const float* eg  = (const float*)d_in[14];
  const float* ebt = (const float*)d_in[15];
  const float* eW2 = (const float*)d_in[16];
  const float* eb2 = (const float*)d_in[17];
  const float* gv  = (const float*)d_in[18];
  const float* gatW[3]  = {(const float*)d_in[19], (const float*)d_in[23], (const float*)d_in[27]};
  const float* gatAS[3] = {(const float*)d_in[20], (const float*)d_in[24], (const float*)d_in[28]};
  const float* gatAD[3] = {(const float*)d_in[21], (const float*)d_in[25], (const float*)d_in[29]};
  const float* gatB[3]  = {(const float*)d_in[22], (const float*)d_in[26], (const float*)d_in[30]};
  const void* maskraw = d_in[31];
  const int* esrc = (const int*)d_in[32];
  const int* edst = (const int*)d_in[33];
  const int E = in_sizes[32];

  if (ws_size < WSNEED) { k_sentinel<<<1, 1, 0, stream>>>((float*)d_out); return; }

  char* ws = (char*)d_ws;
  float* hA   = (float*)(ws + oA);
  float* hB   = (float*)(ws + oB);
  float* sS   = (float*)(ws + oSS);
  float* sD   = (float*)(ws + oSD);
  float* z    = (float*)(ws + oZ);
  float* p    = (float*)(ws + oP);
  float* tw   = (float*)(ws + oTW);
  int*   ti   = (int*)(ws + oTI);
  int*   plist= (int*)(ws + oPL);
  int*   pexp = (int*)(ws + oPE);
  float* ptw  = (float*)(ws + oPW);
  int*   deg  = (int*)(ws + oDG);
  int*   offs = (int*)(ws + oOF);
  int*   ccnt = (int*)(ws + oCC);
  int*   csrc = (int*)(ws + oCS);
  int*   ceid = (int*)(ws + oCE);
  int*   zsm  = (int*)(ws + oZS);
  int*   offs9= (int*)(ws + o9);
  int*   big  = (int*)(ws + oBG);
  int*   bigoff=(int*)(ws + oBO);
  int*   wsmask=(int*)(ws + oMK);
  double* Wc  = (double*)(ws + oWC);
  unsigned short* PBh = (unsigned short*)(ws + oPBh);
  unsigned short* PBl = (unsigned short*)(ws + oPBl);
  unsigned short* G0h = (unsigned short*)(ws + oG0h);
  unsigned short* G0l = (unsigned short*)(ws + oG0l);
  unsigned short* G1h = (unsigned short*)(ws + oG1h);
  unsigned short* G1l = (unsigned short*)(ws + oG1l);
  unsigned short* G2h = (unsigned short*)(ws + oG2h);
  unsigned short* G2l = (unsigned short*)(ws + oG2l);
  unsigned short* E1h = (unsigned short*)(ws + oE1h);
  unsigned short* E1l = (unsigned short*)(ws + oE1l);
  unsigned short* E2h = (unsigned short*)(ws + oE2h);
  unsigned short* E2l = (unsigned short*)(ws + oE2l);
  int*   flags = (int*)(ws + oFL);
  float* gWt   = (float*)(ws + oGWT);
  unsigned short* Gh[3] = {G0h, G1h, G2h};
  unsigned short* Gl_[3] = {G0l, G1l, G2l};
  float* x = (float*)d_out;   // packed proj output lives in d_out until final write

  const int eblk = (E + 255) / 256;

  // zero per-call state (zsm covers counts/cnt2/nbig/maskflag/nflag)
  hipMemsetAsync(zsm, 0, 256, stream);
  hipMemsetAsync(deg, 0, (size_t)(NT + 3) * 4, stream);
  hipMemsetAsync(ccnt, 0, (size_t)(NT + 3) * 4, stream);

  // mask canonicalization
  k_mask_flag<<<64, 256, 0, stream>>>((const unsigned int*)maskraw, zsm + 17);
  k_mask_canon<<<NV / 256, 256, 0, stream>>>(maskraw, zsm + 17, wsmask);

  // 0) weight transposes + bf16 splits (fragment-major global layout)
  k_tsplit<<<dim3(16, 4, 1), 256, 0, stream>>>(Wv, 1024, 256, 2304, 0,    0, 0, PBh, PBl);
  k_tsplit<<<dim3(8,  4, 1), 256, 0, stream>>>(Wa, 512,  256, 2304, 1024, 0, 0, PBh, PBl);
  k_tsplit<<<dim3(12, 4, 1), 256, 0, stream>>>(Wt, 768,  256, 2304, 1536, 0, 0, PBh, PBl);
  k_tsplit<<<dim3(4, 16, 1), 256, 0, stream>>>(gatW[0], 256, 1024, 256, 0, 0, 0, G0h, G0l);
  k_tsplit<<<dim3(16,16, 1), 256, 0, stream>>>(gatW[1], 1024, 1024, 1024, 0, 0, 0, G1h, G1l);
  k_tsplit<<<dim3(16,16, 1), 256, 0, stream>>>(gatW[2], 1024, 1024, 1024, 0, 0, 0, G2h, G2l);
  k_tsplit<<<dim3(4, 4, 8),  256, 0, stream>>>(eW1, 256, 256, 256, 0, 65536, 65536, E1h, E1l);
  k_tsplit<<<dim3(4, 4, 8),  256, 0, stream>>>(eW2, 256, 256, 256, 0, 65536, 65536, E2h, E2l);

  // 1) modal projection (+bias)/3 + mask token  -> x (PACKED, fused in epilogue)
  gemm_m<1><<<dim3(2, 512), 256, 0, stream>>>(
      NV, 2304, fv, 1024, fa, 512, ft, 768,
      PBh, PBl, 0, x, DMOD,
      bv, wsmask, mtok, ba, bt,
      nullptr, nullptr, nullptr, nullptr);

  // 2) MoE: fast f32 gate from packed x + f64 fix for near-ties, then sparse expert GEMMs
  k_wc<<<2306, 64, 0, stream>>>(Wv, Wa, Wt, bv, ba, bt, mtok, gW, gb, Wc);
  k_gwt<<<8, 256, 0, stream>>>(gW, gWt);
  k_gate_f32<<<NV / 4, 256, 0, stream>>>((const unsigned*)x, gWt, gb, Wc, wsmask,
                                         tw, ti, flags, zsm + 18);
  k_gate_fix<<<64, 256, 0, stream>>>(fv, fa, ft, Wc, wsmask, flags, zsm + 18, tw, ti);
  k_count<<<NV / 256, 256, 0, stream>>>(ti, zsm);
  k_moe_offs<<<1, 64, 0, stream>>>(zsm, offs9);
  k_moe_fill<<<CAPR / 256, 256, 0, stream>>>(offs9, plist, pexp);
  k_moe_scatter<<<NV / 256, 256, 0, stream>>>(ti, tw, offs9, zsm + 8, plist, ptw);
  gemm_m<2><<<dim3(2, CAPR / 128), 256, 0, stream>>>(
      CAPR, DMOD, nullptr, 0, nullptr, 0, nullptr, 0,
      E1h, E1l, (long)DMOD * DMOD, hB, DMOD,
      eb1, nullptr, nullptr, nullptr, nullptr,
      plist, pexp, nullptr, x);
  k_ln_gelu<<<CAPR, 256, 0, stream>>>(hB, plist, pexp, eg, ebt);   // writes packed
  hipMemsetAsync(hA, 0, (size_t)NT * DMOD * 4, stream);
  k_set_global<<<1, 256, 0, stream>>>(hA, gv);
  gemm_m<3><<<dim3(2, CAPR / 128), 256, 0, stream>>>(
      CAPR, DMOD, hB, DMOD, nullptr, 0, nullptr, 0,
      E2h, E2l, (long)DMOD * DMOD, hA, DMOD,
      eb2, nullptr, nullptr, nullptr, nullptr,
      plist, pexp, ptw, nullptr);
  // pack layer-0 h (f32 atomics above) -> packed for GEMM0
  k_pack<<<(int)(((size_t)NT * DMOD / 4 + 255) / 256), 256, 0, stream>>>(hA, (size_t)NT * DMOD);

  // 3) CSR (edges identical for all layers)
  k_deg<<<eblk, 256, 0, stream>>>(edst, deg, E);
  k_scan<<<1, 1024, 0, stream>>>(deg, offs);
  k_csr_scatter<<<eblk, 256, 0, stream>>>(esrc, edst, offs, ccnt, csrc, ceid, E);
  k_biglist<<<1, 256, 0, stream>>>(offs, zsm + 16, big, bigoff);

  // 4) 3 GAT layers: GEMM xw (hB) -> attention -> aggregate (packed) back into hA
  for (int l = 0; l < 3; ++l) {
    const int kin = (l == 0) ? DMOD : DHID;
    gemm_m<0><<<4104, 256, 0, stream>>>(
        NT, kin, hA, kin, nullptr, 0, nullptr, 0,
        Gh[l], Gl_[l], 0, hB, DHID,
        nullptr, nullptr, nullptr, nullptr, nullptr,
        nullptr, nullptr, nullptr, nullptr);
    k_attn_s<<<(NT + 3) / 4, 256, 0, stream>>>(hB, gatAS[l], gatAD[l], sS, sD);
    hipMemsetAsync(z, 0, nf4, stream);
    k_edge_z<<<eblk, 256, 0, stream>>>(esrc, edst, sS, sD, p, z, E);
    k_agg_small<<<NT, 256, 0, stream>>>(hB, p, z, offs, csrc, ceid, gatB[l], hA);
    k_agg_big<<<4096, 256, 0, stream>>>(hB, p, z, offs, csrc, ceid, zsm + 16, big, bigoff, hA);
    k_pack_rows<<<64, 256, 0, stream>>>(hA, zsm + 16, big);
  }

  // 5) mean over heads (unpack hi+lo) -> d_out
  k_head_mean<<<(int)(((size_t)NT * 64 + 255) / 256), 256, 0, stream>>>(hA, (float*)d_out);
}